// Round 12
// baseline (133.254 us; speedup 1.0000x reference)
//
#include <hip/hip_runtime.h>

// ---------------------------------------------------------------------------
// LatentMixtureAllRNNAgent: per-agent fc1 -> GRU cell -> fc2 on MI355X.
// Round 12: k2 with mt=4 (64 rows x 32 cols per wave): B-fragment reuse
// doubled -> loads/output -37.5% (k2 was load-issue bound at 74us with all
// pipes <30%). Rowsums moved to k1 (exact f32, stored per-agent-row in ws;
// k2 reads float4 broadcasts) -> -8 MFMA/ks and -32 AGPR in k2.
// Accs R,I,T,G[4][2] = 128 AGPR + ~110 VGPR -> 2 waves/SIMD (deliberate
// occupancy-for-efficiency trade; TLP plateaued at 3 anyway).
// Numerics: same bf16 operands as rounds 2-11 (absmax 1.0); rowsum f32
// order = rounds 5-7 scheme (proven).
// ---------------------------------------------------------------------------

typedef __attribute__((ext_vector_type(4))) float f32x4;
typedef __attribute__((ext_vector_type(8))) short s8;     // 8 bf16 (4 VGPRs)
typedef __attribute__((ext_vector_type(4))) unsigned short us4;
typedef __attribute__((ext_vector_type(8))) unsigned short us8;

#define QSIZE   983040      /* 32768*30 */
#define W1H_OFF 0
#define W1L_OFF 524288
#define WIH_OFF 1048576
#define WHH_OFF 2621440
#define W2T_OFF 4194304
#define XB_OFF  4259840                 /* X fragments:   8a x 256rb x 4096 */
#define HB_OFF  12648448                /* h_in fragments: same */
#define RSX_U   21037056                /* f32 rowsum(x):   8a x 4096 rows  */
#define RSH_U   21102592                /* f32 rowsum(h_in): same           */
#define WS_NEED_NEW 42336256ull        /* bytes */

static __device__ __forceinline__ unsigned short f2bf(float f) {
  union { float f; unsigned u; } v; v.f = f;
  unsigned r = v.u + 0x7FFFu + ((v.u >> 16) & 1u);   // RNE
  return (unsigned short)(r >> 16);
}
static __device__ __forceinline__ float bf2f(unsigned short u) {
  union { unsigned u; float f; } v; v.u = ((unsigned)u) << 16;
  return v.f;
}
static __device__ __forceinline__ float sigm(float x) {
  return 1.0f / (1.0f + __expf(-x));
}
static __device__ __forceinline__ float tanh_(float x) {
  return 1.0f - 2.0f / (__expf(2.0f * x) + 1.0f);
}

// ---- prep: f32 [a][k][n] -> bf16 fragment layout [a][cb][ks][l4][l16][8] ---
__global__ void prep_weights(const float* __restrict__ fc1w,
                             const float* __restrict__ rihw,
                             const float* __restrict__ rhhw,
                             const float* __restrict__ fc2w,
                             unsigned short* __restrict__ ws) {
  int q = blockIdx.x * 256 + threadIdx.x;   // one us4 (4 k-values) per thread
  if (q < 131072) {                         // fc1: hi + lo, 8a x 16cb x 1024
    int a = q >> 14, rem = q & 16383;
    int cb = rem >> 10, s = rem & 1023;
    int ks = s >> 7, l4 = (s >> 5) & 3, l16 = (s >> 1) & 15, hf = s & 1;
    int n = cb * 16 + l16, k0 = ks * 32 + l4 * 8 + hf * 4;
    const float* sp = fc1w + a * 65536 + k0 * 256 + n;
    float v0 = sp[0], v1 = sp[256], v2 = sp[512], v3 = sp[768];
    us4 hi = { f2bf(v0), f2bf(v1), f2bf(v2), f2bf(v3) };
    us4 lo = { f2bf(v0 - bf2f(hi[0])), f2bf(v1 - bf2f(hi[1])),
               f2bf(v2 - bf2f(hi[2])), f2bf(v3 - bf2f(hi[3])) };
    int o = a * 65536 + cb * 4096 + ks * 512 + l4 * 128 + l16 * 8 + hf * 4;
    *(us4*)(ws + W1H_OFF + o) = hi;
    *(us4*)(ws + W1L_OFF + o) = lo;
  } else if (q < 524288) {                  // rnn_ih centered: 8a x 48cb
    int t = q - 131072;
    int a = t / 49152, rem = t % 49152;
    int cb = rem >> 10, s = rem & 1023;
    int ks = s >> 7, l4 = (s >> 5) & 3, l16 = (s >> 1) & 15, hf = s & 1;
    int n = cb * 16 + l16, k0 = ks * 32 + l4 * 8 + hf * 4;
    const float* sp = rihw + a * 196608 + k0 * 768 + n;
    us4 v = { f2bf(sp[0] - 0.5f), f2bf(sp[768] - 0.5f),
              f2bf(sp[1536] - 0.5f), f2bf(sp[2304] - 0.5f) };
    *(us4*)(ws + WIH_OFF + a * 196608 + cb * 4096 + ks * 512 + l4 * 128
            + l16 * 8 + hf * 4) = v;
  } else if (q < 917504) {                  // rnn_hh centered
    int t = q - 524288;
    int a = t / 49152, rem = t % 49152;
    int cb = rem >> 10, s = rem & 1023;
    int ks = s >> 7, l4 = (s >> 5) & 3, l16 = (s >> 1) & 15, hf = s & 1;
    int n = cb * 16 + l16, k0 = ks * 32 + l4 * 8 + hf * 4;
    const float* sp = rhhw + a * 196608 + k0 * 768 + n;
    us4 v = { f2bf(sp[0] - 0.5f), f2bf(sp[768] - 0.5f),
              f2bf(sp[1536] - 0.5f), f2bf(sp[2304] - 0.5f) };
    *(us4*)(ws + WHH_OFF + a * 196608 + cb * 4096 + ks * 512 + l4 * 128
            + l16 * 8 + hf * 4) = v;
  } else if (q < 933888) {                  // fc2: 8a x 2cb, pad n>=30 -> 0
    int t = q - 917504;
    int a = t >> 11, rem = t & 2047;
    int cb = rem >> 10, s = rem & 1023;
    int ks = s >> 7, l4 = (s >> 5) & 3, l16 = (s >> 1) & 15, hf = s & 1;
    int n = cb * 16 + l16, k0 = ks * 32 + l4 * 8 + hf * 4;
    us4 v = { 0, 0, 0, 0 };
    if (n < 30) {
      const float* sp = fc2w + a * 7680 + k0 * 30 + n;
      v = (us4){ f2bf(sp[0]), f2bf(sp[30]), f2bf(sp[60]), f2bf(sp[90]) };
    }
    *(us4*)(ws + W2T_OFF + a * 8192 + cb * 4096 + ks * 512 + l4 * 128
            + l16 * 8 + hf * 4) = v;
  }
}

// ------- stage 32x256 f32 tile -> split bf16 (hi p0, lo p1), 256 thr --------
static __device__ __forceinline__ void stage_split(unsigned short* p0,
                                                   unsigned short* p1,
                                                   const float* __restrict__ src,
                                                   int rowbase, int a, int tid) {
#pragma unroll
  for (int k = 0; k < 8; ++k) {
    int j = tid + k * 256;
    int r = j >> 6;
    int c4 = (j & 63) << 2;
    const float* p = src + ((((rowbase + r) << 3) + a) << 8) + c4;
    float4 v = *(const float4*)p;
    us4 hi = { f2bf(v.x), f2bf(v.y), f2bf(v.z), f2bf(v.w) };
    us4 lo = { f2bf(v.x - bf2f(hi[0])), f2bf(v.y - bf2f(hi[1])),
               f2bf(v.z - bf2f(hi[2])), f2bf(v.w - bf2f(hi[3])) };
    int idx = ((r << 8) + c4) ^ ((r & 7) << 3);   // XOR swizzle (16B blocks)
    *(us4*)(p0 + idx) = hi;
    *(us4*)(p1 + idx) = lo;
  }
}

// ------------- stage 32x256 f32 tile -> single bf16 plane, 256 thr ----------
static __device__ __forceinline__ void stage_single(unsigned short* p,
                                                    const float* __restrict__ src,
                                                    int rowbase, int a, int tid) {
#pragma unroll
  for (int k = 0; k < 8; ++k) {
    int j = tid + k * 256;
    int r = j >> 6;
    int c4 = (j & 63) << 2;
    const float* sp = src + ((((rowbase + r) << 3) + a) << 8) + c4;
    float4 v = *(const float4*)sp;
    us4 hi = { f2bf(v.x), f2bf(v.y), f2bf(v.z), f2bf(v.w) };
    int idx = ((r << 8) + c4) ^ ((r & 7) << 3);
    *(us4*)(p + idx) = hi;
  }
}

// ---- 32x64 GEMM over K=256, B from fragment layout (contiguous loads) ------
static __device__ __forceinline__ void mma64f(const unsigned short* lds,
                                              const unsigned short* __restrict__ wf,
                                              int cb0, int lane, int l16, int l4,
                                              f32x4 (&acc)[2][4]) {
#pragma unroll
  for (int ks = 0; ks < 8; ++ks) {
    s8 af[2], bw[4];
#pragma unroll
    for (int mt = 0; mt < 2; ++mt) {
      int row = mt * 16 + l16;
      int idx = ((row << 8) + ks * 32 + 8 * l4) ^ ((row & 7) << 3);
      af[mt] = *(const s8*)(lds + idx);
    }
#pragma unroll
    for (int nt = 0; nt < 4; ++nt)
      bw[nt] = *(const s8*)(wf + (cb0 + nt) * 4096 + ks * 512 + lane * 8);
#pragma unroll
    for (int mt = 0; mt < 2; ++mt)
#pragma unroll
      for (int nt = 0; nt < 4; ++nt)
        acc[mt][nt] = __builtin_amdgcn_mfma_f32_16x16x32_bf16(
            af[mt], bw[nt], acc[mt][nt], 0, 0, 0);
  }
}

// ---- 32x16 GEMM over K=256, fragment B (fallback kernel) -------------------
static __device__ __forceinline__ void mma16f(const unsigned short* lds,
                                              const unsigned short* __restrict__ wf,
                                              int cb, int lane, int l16, int l4,
                                              f32x4 (&acc)[2]) {
#pragma unroll
  for (int ks = 0; ks < 8; ++ks) {
    s8 bw = *(const s8*)(wf + cb * 4096 + ks * 512 + lane * 8);
#pragma unroll
    for (int mt = 0; mt < 2; ++mt) {
      int row = mt * 16 + l16;
      int idx = ((row << 8) + ks * 32 + 8 * l4) ^ ((row & 7) << 3);
      s8 af = *(const s8*)(lds + idx);
      acc[mt] = __builtin_amdgcn_mfma_f32_16x16x32_bf16(af, bw, acc[mt], 0, 0, 0);
    }
  }
}

// ====== K1: fc1 -> X fragments; h_in -> fragments; exact rowsums -> ws ======
__global__ __launch_bounds__(256, 2) void k1_fc1(
    const float* __restrict__ inp, const float* __restrict__ hin,
    const float* __restrict__ b1, unsigned short* __restrict__ ws) {
  __shared__ __align__(16) unsigned short P0[32 * 256];
  __shared__ __align__(16) unsigned short P1[32 * 256];
  __shared__ float RSXP[8][32], RSHP[8][32];
  const int tid = threadIdx.x;
  const int a = blockIdx.x & 7;
  const int rt = blockIdx.x >> 3;
  const int rowbase = rt * 32;
  const int lane = tid & 63, w = tid >> 6;
  const int l16 = lane & 15, l4 = lane >> 4;
  const int n0 = w * 64;

  stage_split(P0, P1, inp, rowbase, a, tid);
  __syncthreads();

  f32x4 XA[2][4];
#pragma unroll
  for (int mt = 0; mt < 2; ++mt)
#pragma unroll
    for (int nt = 0; nt < 4; ++nt) XA[mt][nt] = (f32x4){0.f, 0.f, 0.f, 0.f};
  mma64f(P0, ws + W1H_OFF + a * 65536, w * 4, lane, l16, l4, XA);
  mma64f(P1, ws + W1H_OFF + a * 65536, w * 4, lane, l16, l4, XA);
  mma64f(P0, ws + W1L_OFF + a * 65536, w * 4, lane, l16, l4, XA);
  __syncthreads();                           // all LDS reads done

  // write x bf16 -> P0 (swizzled); stage h_in bf16 -> P1 (swizzled)
#pragma unroll
  for (int nt = 0; nt < 4; ++nt) {
    int col = n0 + nt * 16 + l16;
    float bb = b1[a * 256 + col];
#pragma unroll
    for (int mt = 0; mt < 2; ++mt)
#pragma unroll
      for (int r = 0; r < 4; ++r) {
        float v = fmaxf(XA[mt][nt][r] + bb, 0.f);
        int row = mt * 16 + l4 * 4 + r;
        P0[((row << 8) + col) ^ ((row & 7) << 3)] = f2bf(v);
      }
  }
  stage_single(P1, hin, rowbase, a, tid);
  __syncthreads();

  // fragment-dump: P0 -> XF, P1 -> HF (contiguous us8 wave stores)
  const int rbg = (a << 8) + rt * 2;
#pragma unroll
  for (int i = 0; i < 4; ++i) {
    int c = tid + i * 256;                   // 0..1023 us8 chunks
    int rb = c >> 9, s = c & 511;            // s = ks*64 + l4*16 + l16
    int row = rb * 16 + (s & 15);
    int col = ((s >> 6) << 5) + (((s >> 4) & 3) << 3);
    int idx = ((row << 8) + col) ^ ((row & 7) << 3);
    *(us8*)(ws + XB_OFF + (rbg + rb) * 4096 + s * 8) = *(const us8*)(P0 + idx);
    *(us8*)(ws + HB_OFF + (rbg + rb) * 4096 + s * 8) = *(const us8*)(P1 + idx);
  }

  // exact f32 rowsums of the bf16 tiles -> ws (per-agent-row layout)
  {
    int row = tid >> 3, qd = tid & 7;
    float sx = 0.f, sh = 0.f;
#pragma unroll
    for (int i = 0; i < 8; ++i) {
      int c = qd * 32 + i * 4;
      int idx = ((row << 8) + c) ^ ((row & 7) << 3);
      us4 vx = *(const us4*)(P0 + idx);
      us4 vh = *(const us4*)(P1 + idx);
      sx += bf2f(vx[0]) + bf2f(vx[1]) + bf2f(vx[2]) + bf2f(vx[3]);
      sh += bf2f(vh[0]) + bf2f(vh[1]) + bf2f(vh[2]) + bf2f(vh[3]);
    }
    RSXP[qd][row] = sx; RSHP[qd][row] = sh;
  }
  __syncthreads();
  if (tid < 32) {
    float sx = 0.f, sh = 0.f;
#pragma unroll
    for (int qd = 0; qd < 8; ++qd) { sx += RSXP[qd][tid]; sh += RSHP[qd][tid]; }
    float* rsxg = (float*)(ws + RSX_U);
    float* rshg = (float*)(ws + RSH_U);
    rsxg[a * 4096 + rowbase + tid] = sx;
    rshg[a * 4096 + rowbase + tid] = sh;
  }
}

// ====== K2: mt=4 single-pass — 64 rows x 32 cols per wave ===================
__global__ __launch_bounds__(256, 1) void k2_gates_nw(
    const float* __restrict__ hin, const float* __restrict__ bih,
    const float* __restrict__ bhh, const unsigned short* __restrict__ ws,
    float* __restrict__ out) {
  const int lane = threadIdx.x & 63;
  const int w    = threadIdx.x >> 6;
  const int bid  = blockIdx.x;
  const int a    = bid & 7;                 // agent == XCD
  const int g    = bid >> 3;                // 0..127
  const int rt   = g >> 1;                  // 64-row tile 0..63 (slow)
  const int cs   = (g & 1) * 4 + w;         // col-slice 0..7
  const int rowbase = rt * 64;
  const int n0   = cs * 32;
  const int l16  = lane & 15, l4 = lane >> 4;

  const unsigned short* XF = ws + XB_OFF + ((a << 8) + rt * 4) * 4096 + lane * 8;
  const unsigned short* HF = ws + HB_OFF + ((a << 8) + rt * 4) * 4096 + lane * 8;
  const unsigned short* WihR = ws + WIH_OFF + a * 196608 + (cs * 2) * 4096 + lane * 8;
  const unsigned short* WhhR = ws + WHH_OFF + a * 196608 + (cs * 2) * 4096 + lane * 8;

  f32x4 R[4][2], I[4][2], T[4][2], G[4][2];
#pragma unroll
  for (int mt = 0; mt < 4; ++mt)
#pragma unroll
    for (int nt = 0; nt < 2; ++nt) {
      R[mt][nt] = (f32x4){0.f, 0.f, 0.f, 0.f};
      I[mt][nt] = (f32x4){0.f, 0.f, 0.f, 0.f};
      T[mt][nt] = (f32x4){0.f, 0.f, 0.f, 0.f};
      G[mt][nt] = (f32x4){0.f, 0.f, 0.f, 0.f};
    }

  // ---- single pass: 20 loads, 48 MFMA per ks ----
#pragma unroll 1
  for (int ks = 0; ks < 8; ++ks) {
    const int ko = ks * 512;
    s8 ax[4], ah[4];
#pragma unroll
    for (int mt = 0; mt < 4; ++mt) {
      ax[mt] = *(const s8*)(XF + mt * 4096 + ko);
      ah[mt] = *(const s8*)(HF + mt * 4096 + ko);
    }
    s8 bxr[2], bhr[2], bxi[2], bhi[2], bxn[2], bhn[2];
#pragma unroll
    for (int nt = 0; nt < 2; ++nt) {
      bxr[nt] = *(const s8*)(WihR + nt * 4096 + ko);
      bhr[nt] = *(const s8*)(WhhR + nt * 4096 + ko);
      bxi[nt] = *(const s8*)(WihR + (16 + nt) * 4096 + ko);
      bhi[nt] = *(const s8*)(WhhR + (16 + nt) * 4096 + ko);
      bxn[nt] = *(const s8*)(WihR + (32 + nt) * 4096 + ko);
      bhn[nt] = *(const s8*)(WhhR + (32 + nt) * 4096 + ko);
    }
#pragma unroll
    for (int mt = 0; mt < 4; ++mt)
#pragma unroll
      for (int nt = 0; nt < 2; ++nt) {
        R[mt][nt] = __builtin_amdgcn_mfma_f32_16x16x32_bf16(ax[mt], bxr[nt], R[mt][nt], 0, 0, 0);
        R[mt][nt] = __builtin_amdgcn_mfma_f32_16x16x32_bf16(ah[mt], bhr[nt], R[mt][nt], 0, 0, 0);
        I[mt][nt] = __builtin_amdgcn_mfma_f32_16x16x32_bf16(ax[mt], bxi[nt], I[mt][nt], 0, 0, 0);
        I[mt][nt] = __builtin_amdgcn_mfma_f32_16x16x32_bf16(ah[mt], bhi[nt], I[mt][nt], 0, 0, 0);
        G[mt][nt] = __builtin_amdgcn_mfma_f32_16x16x32_bf16(ax[mt], bxn[nt], G[mt][nt], 0, 0, 0);
        T[mt][nt] = __builtin_amdgcn_mfma_f32_16x16x32_bf16(ah[mt], bhn[nt], T[mt][nt], 0, 0, 0);
      }
  }

  // ---- epilogue: rowsum broadcasts, gates, combine, store h ----
  const float* rsxg = (const float*)(ws + RSX_U) + a * 4096 + rowbase;
  const float* rshg = (const float*)(ws + RSH_U) + a * 4096 + rowbase;
#pragma unroll
  for (int mt = 0; mt < 4; ++mt) {
    float4 sx4 = *(const float4*)(rsxg + mt * 16 + l4 * 4);
    float4 sh4 = *(const float4*)(rshg + mt * 16 + l4 * 4);
    float rsx[4] = { sx4.x, sx4.y, sx4.z, sx4.w };
    float rsh[4] = { sh4.x, sh4.y, sh4.z, sh4.w };
#pragma unroll
    for (int nt = 0; nt < 2; ++nt) {
      int col = n0 + nt * 16 + l16;
      float br = bih[a * 768 + col] + bhh[a * 768 + col];
      float bi = bih[a * 768 + 256 + col] + bhh[a * 768 + 256 + col];
      float bnh = bhh[a * 768 + 512 + col];
      float bni = bih[a * 768 + 512 + col];
#pragma unroll
      for (int r = 0; r < 4; ++r) {
        float rg = sigm(R[mt][nt][r] + 0.5f * (rsx[r] + rsh[r]) + br);
        float t  = rg * (T[mt][nt][r] + 0.5f * rsh[r] + bnh);
        float ng = tanh_(G[mt][nt][r] + 0.5f * rsx[r] + bni + t);
        float ig = sigm(I[mt][nt][r] + 0.5f * (rsx[r] + rsh[r]) + bi);
        int row = mt * 16 + l4 * 4 + r;
        int flat = ((rowbase + row) << 3) + a;
        float hv = hin[(flat << 8) + col];
        out[QSIZE + (flat << 8) + col] = ng + ig * (hv - ng);
      }
    }
  }
}

// ========================== K3: fc2 -> q (out) ==============================
__global__ __launch_bounds__(128) void k3_fc2(
    const float* __restrict__ b2, const unsigned short* __restrict__ ws,
    float* __restrict__ out) {
  __shared__ __align__(16) unsigned short HB[32 * 256];
  const int tid = threadIdx.x;
  const int a = blockIdx.x & 7;
  const int rowbase = (blockIdx.x >> 3) * 32;
  const int lane = tid & 63, w = tid >> 6;
  const int l16 = lane & 15, l4 = lane >> 4;

#pragma unroll
  for (int k = 0; k < 16; ++k) {
    int j = tid + k * 128;
    int r = j >> 6;
    int c4 = (j & 63) << 2;
    const float* sp = out + QSIZE + ((((rowbase + r) << 3) + a) << 8) + c4;
    float4 v = *(const float4*)sp;
    us4 hi = { f2bf(v.x), f2bf(v.y), f2bf(v.z), f2bf(v.w) };
    int idx = ((r << 8) + c4) ^ ((r & 7) << 3);
    *(us4*)(HB + idx) = hi;
  }
  __syncthreads();

  f32x4 qa[2];
  qa[0] = (f32x4){0.f, 0.f, 0.f, 0.f};
  qa[1] = (f32x4){0.f, 0.f, 0.f, 0.f};
#pragma unroll
  for (int ks = 0; ks < 8; ++ks) {
    int row = w * 16 + l16;
    int idx = ((row << 8) + ks * 32 + 8 * l4) ^ ((row & 7) << 3);
    s8 af = *(const s8*)(HB + idx);
#pragma unroll
    for (int nt = 0; nt < 2; ++nt) {
      s8 bw = *(const s8*)(ws + W2T_OFF + a * 8192 + nt * 4096 + ks * 512 + lane * 8);
      qa[nt] = __builtin_amdgcn_mfma_f32_16x16x32_bf16(af, bw, qa[nt], 0, 0, 0);
    }
  }
#pragma unroll
  for (int nt = 0; nt < 2; ++nt) {
    int col = nt * 16 + l16;
    if (col < 30) {
      float bb = b2[a * 30 + col];
#pragma unroll
      for (int r = 0; r < 4; ++r) {
        int row = w * 16 + l4 * 4 + r;
        out[(((rowbase + row) << 3) + a) * 30 + col] = fmaxf(qa[nt][r] + bb, 0.f);
      }
    }
  }
}

// ======= fallback (ws too small for XF/HF): fused kernel, fragment W ========
__global__ __launch_bounds__(256, 2) void fused_agent_rnn(
    const float* __restrict__ inp,  const float* __restrict__ hin,
    const float* __restrict__ b1,   const float* __restrict__ bih,
    const float* __restrict__ bhh,  const float* __restrict__ b2,
    const unsigned short* __restrict__ ws, float* __restrict__ out) {
  __shared__ __align__(16) unsigned short P0[32 * 256];
  __shared__ __align__(16) unsigned short P1[32 * 256];
  __shared__ float RSXP[8][32], RSHP[8][32];
  __shared__ float RSX[32], RSH[32];

  const int tid = threadIdx.x;
  const int a = blockIdx.x & 7;
  const int rowbase = (blockIdx.x >> 3) * 32;
  const int lane = tid & 63, w = tid >> 6;
  const int l16 = lane & 15, l4 = lane >> 4;
  const int n0 = w * 64;

  stage_split(P0, P1, inp, rowbase, a, tid);
  __syncthreads();
  {
    f32x4 XA[2][4];
#pragma unroll
    for (int mt = 0; mt < 2; ++mt)
#pragma unroll
      for (int nt = 0; nt < 4; ++nt) XA[mt][nt] = (f32x4){0.f, 0.f, 0.f, 0.f};
    mma64f(P0, ws + W1H_OFF + a * 65536, w * 4, lane, l16, l4, XA);
    mma64f(P1, ws + W1H_OFF + a * 65536, w * 4, lane, l16, l4, XA);
    mma64f(P0, ws + W1L_OFF + a * 65536, w * 4, lane, l16, l4, XA);
    __syncthreads();
#pragma unroll
    for (int nt = 0; nt < 4; ++nt) {
      int col = n0 + nt * 16 + l16;
      float bb = b1[a * 256 + col];
#pragma unroll
      for (int mt = 0; mt < 2; ++mt)
#pragma unroll
        for (int r = 0; r < 4; ++r) {
          float v = fmaxf(XA[mt][nt][r] + bb, 0.f);
          int row = mt * 16 + l4 * 4 + r;
          P0[((row << 8) + col) ^ ((row & 7) << 3)] = f2bf(v);
        }
    }
  }
  stage_single(P1, hin, rowbase, a, tid);
  __syncthreads();
  {
    int row = tid >> 3, qd = tid & 7;
    float sx = 0.f, sh = 0.f;
#pragma unroll
    for (int i = 0; i < 8; ++i) {
      int c = qd * 32 + i * 4;
      int idx = ((row << 8) + c) ^ ((row & 7) << 3);
      us4 vx = *(const us4*)(P0 + idx);
      us4 vh = *(const us4*)(P1 + idx);
      sx += bf2f(vx[0]) + bf2f(vx[1]) + bf2f(vx[2]) + bf2f(vx[3]);
      sh += bf2f(vh[0]) + bf2f(vh[1]) + bf2f(vh[2]) + bf2f(vh[3]);
    }
    RSXP[qd][row] = sx; RSHP[qd][row] = sh;
  }
  __syncthreads();
  if (tid < 32) {
    float sx = 0.f, sh = 0.f;
#pragma unroll
    for (int qd = 0; qd < 8; ++qd) { sx += RSXP[qd][tid]; sh += RSHP[qd][tid]; }
    RSX[tid] = sx; RSH[tid] = sh;
  }
  __syncthreads();

  const unsigned short* WihF = ws + WIH_OFF + a * 196608;
  const unsigned short* WhhF = ws + WHH_OFF + a * 196608;

  for (int nt = 0; nt < 4; ++nt) {
    const int col = n0 + nt * 16 + l16;
    const int cb = w * 4 + nt;               // gate-local col-block
    f32x4 R4[2], T4[2], G4[2];
#pragma unroll
    for (int mt = 0; mt < 2; ++mt) R4[mt] = (f32x4){0.f, 0.f, 0.f, 0.f};
    mma16f(P0, WihF, cb, lane, l16, l4, R4);
    mma16f(P1, WhhF, cb, lane, l16, l4, R4);
    {
      float bb = bih[a * 768 + col] + bhh[a * 768 + col];
#pragma unroll
      for (int mt = 0; mt < 2; ++mt)
#pragma unroll
        for (int r = 0; r < 4; ++r) {
          int row = mt * 16 + l4 * 4 + r;
          R4[mt][r] = sigm(R4[mt][r] + 0.5f * (RSX[row] + RSH[row]) + bb);
        }
    }
#pragma unroll
    for (int mt = 0; mt < 2; ++mt) T4[mt] = (f32x4){0.f, 0.f, 0.f, 0.f};
    mma16f(P1, WhhF, 32 + cb, lane, l16, l4, T4);
    {
      float bb = bhh[a * 768 + 512 + col];
#pragma unroll
      for (int mt = 0; mt < 2; ++mt)
#pragma unroll
        for (int r = 0; r < 4; ++r) {
          int row = mt * 16 + l4 * 4 + r;
          T4[mt][r] = R4[mt][r] * (T4[mt][r] + 0.5f * RSH[row] + bb);
        }
    }
#pragma unroll
    for (int mt = 0; mt < 2; ++mt) G4[mt] = (f32x4){0.f, 0.f, 0.f, 0.f};
    mma16f(P0, WihF, 32 + cb, lane, l16, l4, G4);
    {
      float bb = bih[a * 768 + 512 + col];
#pragma unroll
      for (int mt = 0; mt < 2; ++mt)
#pragma unroll
        for (int r = 0; r < 4; ++r) {
          int row = mt * 16 + l4 * 4 + r;
          T4[mt][r] = tanh_(G4[mt][r] + 0.5f * RSX[row] + bb + T4[mt][r]);
        }
    }
#pragma unroll
    for (int mt = 0; mt < 2; ++mt) G4[mt] = (f32x4){0.f, 0.f, 0.f, 0.f};
    mma16f(P0, WihF, 16 + cb, lane, l16, l4, G4);
    mma16f(P1, WhhF, 16 + cb, lane, l16, l4, G4);
    {
      float bb = bih[a * 768 + 256 + col] + bhh[a * 768 + 256 + col];
#pragma unroll
      for (int mt = 0; mt < 2; ++mt)
#pragma unroll
        for (int r = 0; r < 4; ++r) {
          int row = mt * 16 + l4 * 4 + r;
          float ig = sigm(G4[mt][r] + 0.5f * (RSX[row] + RSH[row]) + bb);
          float hv = bf2f(P1[((row << 8) + col) ^ ((row & 7) << 3)]);
          float ng = T4[mt][r];
          out[QSIZE + ((((rowbase + row) << 3) + a) << 8) + col]
              = ng + ig * (hv - ng);
        }
    }
  }
  __syncthreads();
  stage_single(P0, out + QSIZE, rowbase, a, tid);
  __syncthreads();
  if (w < 2) {
    f32x4 qa[2];
    qa[0] = (f32x4){0.f, 0.f, 0.f, 0.f};
    qa[1] = (f32x4){0.f, 0.f, 0.f, 0.f};
#pragma unroll
    for (int ks = 0; ks < 8; ++ks) {
      int row = w * 16 + l16;
      int idx = ((row << 8) + ks * 32 + 8 * l4) ^ ((row & 7) << 3);
      s8 af = *(const s8*)(P0 + idx);
#pragma unroll
      for (int nt = 0; nt < 2; ++nt) {
        s8 bw = *(const s8*)(ws + W2T_OFF + a * 8192 + nt * 4096 + ks * 512 + lane * 8);
        qa[nt] = __builtin_amdgcn_mfma_f32_16x16x32_bf16(af, bw, qa[nt], 0, 0, 0);
      }
    }
#pragma unroll
    for (int nt = 0; nt < 2; ++nt) {
      int col = nt * 16 + l16;
      if (col < 30) {
        float bb = b2[a * 30 + col];
#pragma unroll
        for (int r = 0; r < 4; ++r) {
          int row = w * 16 + l4 * 4 + r;
          out[(((rowbase + row) << 3) + a) * 30 + col] = fmaxf(qa[nt][r] + bb, 0.f);
        }
      }
    }
  }
}

extern "C" void kernel_launch(void* const* d_in, const int* in_sizes, int n_in,
                              void* d_out, int out_size, void* d_ws, size_t ws_size,
                              hipStream_t stream) {
  const float* inputs = (const float*)d_in[0];
  const float* hidden = (const float*)d_in[1];
  const float* fc1w   = (const float*)d_in[2];
  const float* fc1b   = (const float*)d_in[3];
  const float* rihw   = (const float*)d_in[4];
  const float* rihb   = (const float*)d_in[5];
  const float* rhhw   = (const float*)d_in[6];
  const float* rhhb   = (const float*)d_in[7];
  const float* fc2w   = (const float*)d_in[8];
  const float* fc2b   = (const float*)d_in[9];
  unsigned short* ws  = (unsigned short*)d_ws;
  float* out          = (float*)d_out;

  hipLaunchKernelGGL(prep_weights, dim3(3648), dim3(256), 0, stream,
                     fc1w, rihw, rhhw, fc2w, ws);

  if (ws_size >= WS_NEED_NEW) {
    hipLaunchKernelGGL(k1_fc1, dim3(1024), dim3(256), 0, stream,
                       inputs, hidden, fc1b, ws);
    hipLaunchKernelGGL(k2_gates_nw, dim3(1024), dim3(256), 0, stream,
                       hidden, rihb, rhhb, ws, out);
    hipLaunchKernelGGL(k3_fc2, dim3(1024), dim3(128), 0, stream, fc2b, ws, out);
  } else {
    hipLaunchKernelGGL(fused_agent_rnn, dim3(1024), dim3(256), 0, stream,
                       inputs, hidden, fc1b, rihb, rhhb, fc2b, ws, out);
  }
}

// Round 13
// 103.740 us; speedup vs baseline: 1.2845x; 1.2845x over previous
//
#include <hip/hip_runtime.h>

// ---------------------------------------------------------------------------
// LatentMixtureAllRNNAgent: per-agent fc1 -> GRU cell -> fc2 on MI355X.
// Round 13: k2 = round-11 shape (mt=2, single pass, 3 waves/SIMD) + two
// strictly-positive round-12 pieces: rowsums precomputed in k1 (-4 MFMA/ks,
// -16 AGPR) and LDS-staged A-fragments (32KB/block; 4 waves share the same
// 32 rows -> 4 A-loads/ks move from the bottlenecked global pipe to the idle
// LDS pipe; global loads/wave 128 -> 96). Residency law lesson from r12:
// keep total regs < ~160 for 3 waves/SIMD — occupancy beats per-wave
// efficiency on this kernel.
// Numerics: identical operands to rounds 2-12 (absmax 1.0).
// ---------------------------------------------------------------------------

typedef __attribute__((ext_vector_type(4))) float f32x4;
typedef __attribute__((ext_vector_type(8))) short s8;     // 8 bf16 (4 VGPRs)
typedef __attribute__((ext_vector_type(4))) unsigned short us4;
typedef __attribute__((ext_vector_type(8))) unsigned short us8;

#define QSIZE   983040      /* 32768*30 */
#define W1H_OFF 0
#define W1L_OFF 524288
#define WIH_OFF 1048576
#define WHH_OFF 2621440
#define W2T_OFF 4194304
#define XB_OFF  4259840                 /* X fragments:   8a x 256rb x 4096 */
#define HB_OFF  12648448                /* h_in fragments: same */
#define RSX_U   21037056                /* f32 rowsum(x):   8a x 4096 rows  */
#define RSH_U   21102592                /* f32 rowsum(h_in): same           */
#define WS_NEED_NEW 42336256ull        /* bytes */

static __device__ __forceinline__ unsigned short f2bf(float f) {
  union { float f; unsigned u; } v; v.f = f;
  unsigned r = v.u + 0x7FFFu + ((v.u >> 16) & 1u);   // RNE
  return (unsigned short)(r >> 16);
}
static __device__ __forceinline__ float bf2f(unsigned short u) {
  union { unsigned u; float f; } v; v.u = ((unsigned)u) << 16;
  return v.f;
}
static __device__ __forceinline__ float sigm(float x) {
  return 1.0f / (1.0f + __expf(-x));
}
static __device__ __forceinline__ float tanh_(float x) {
  return 1.0f - 2.0f / (__expf(2.0f * x) + 1.0f);
}

// ---- prep: f32 [a][k][n] -> bf16 fragment layout [a][cb][ks][l4][l16][8] ---
__global__ void prep_weights(const float* __restrict__ fc1w,
                             const float* __restrict__ rihw,
                             const float* __restrict__ rhhw,
                             const float* __restrict__ fc2w,
                             unsigned short* __restrict__ ws) {
  int q = blockIdx.x * 256 + threadIdx.x;   // one us4 (4 k-values) per thread
  if (q < 131072) {                         // fc1: hi + lo, 8a x 16cb x 1024
    int a = q >> 14, rem = q & 16383;
    int cb = rem >> 10, s = rem & 1023;
    int ks = s >> 7, l4 = (s >> 5) & 3, l16 = (s >> 1) & 15, hf = s & 1;
    int n = cb * 16 + l16, k0 = ks * 32 + l4 * 8 + hf * 4;
    const float* sp = fc1w + a * 65536 + k0 * 256 + n;
    float v0 = sp[0], v1 = sp[256], v2 = sp[512], v3 = sp[768];
    us4 hi = { f2bf(v0), f2bf(v1), f2bf(v2), f2bf(v3) };
    us4 lo = { f2bf(v0 - bf2f(hi[0])), f2bf(v1 - bf2f(hi[1])),
               f2bf(v2 - bf2f(hi[2])), f2bf(v3 - bf2f(hi[3])) };
    int o = a * 65536 + cb * 4096 + ks * 512 + l4 * 128 + l16 * 8 + hf * 4;
    *(us4*)(ws + W1H_OFF + o) = hi;
    *(us4*)(ws + W1L_OFF + o) = lo;
  } else if (q < 524288) {                  // rnn_ih centered: 8a x 48cb
    int t = q - 131072;
    int a = t / 49152, rem = t % 49152;
    int cb = rem >> 10, s = rem & 1023;
    int ks = s >> 7, l4 = (s >> 5) & 3, l16 = (s >> 1) & 15, hf = s & 1;
    int n = cb * 16 + l16, k0 = ks * 32 + l4 * 8 + hf * 4;
    const float* sp = rihw + a * 196608 + k0 * 768 + n;
    us4 v = { f2bf(sp[0] - 0.5f), f2bf(sp[768] - 0.5f),
              f2bf(sp[1536] - 0.5f), f2bf(sp[2304] - 0.5f) };
    *(us4*)(ws + WIH_OFF + a * 196608 + cb * 4096 + ks * 512 + l4 * 128
            + l16 * 8 + hf * 4) = v;
  } else if (q < 917504) {                  // rnn_hh centered
    int t = q - 524288;
    int a = t / 49152, rem = t % 49152;
    int cb = rem >> 10, s = rem & 1023;
    int ks = s >> 7, l4 = (s >> 5) & 3, l16 = (s >> 1) & 15, hf = s & 1;
    int n = cb * 16 + l16, k0 = ks * 32 + l4 * 8 + hf * 4;
    const float* sp = rhhw + a * 196608 + k0 * 768 + n;
    us4 v = { f2bf(sp[0] - 0.5f), f2bf(sp[768] - 0.5f),
              f2bf(sp[1536] - 0.5f), f2bf(sp[2304] - 0.5f) };
    *(us4*)(ws + WHH_OFF + a * 196608 + cb * 4096 + ks * 512 + l4 * 128
            + l16 * 8 + hf * 4) = v;
  } else if (q < 933888) {                  // fc2: 8a x 2cb, pad n>=30 -> 0
    int t = q - 917504;
    int a = t >> 11, rem = t & 2047;
    int cb = rem >> 10, s = rem & 1023;
    int ks = s >> 7, l4 = (s >> 5) & 3, l16 = (s >> 1) & 15, hf = s & 1;
    int n = cb * 16 + l16, k0 = ks * 32 + l4 * 8 + hf * 4;
    us4 v = { 0, 0, 0, 0 };
    if (n < 30) {
      const float* sp = fc2w + a * 7680 + k0 * 30 + n;
      v = (us4){ f2bf(sp[0]), f2bf(sp[30]), f2bf(sp[60]), f2bf(sp[90]) };
    }
    *(us4*)(ws + W2T_OFF + a * 8192 + cb * 4096 + ks * 512 + l4 * 128
            + l16 * 8 + hf * 4) = v;
  }
}

// ------- stage 32x256 f32 tile -> split bf16 (hi p0, lo p1), 256 thr --------
static __device__ __forceinline__ void stage_split(unsigned short* p0,
                                                   unsigned short* p1,
                                                   const float* __restrict__ src,
                                                   int rowbase, int a, int tid) {
#pragma unroll
  for (int k = 0; k < 8; ++k) {
    int j = tid + k * 256;
    int r = j >> 6;
    int c4 = (j & 63) << 2;
    const float* p = src + ((((rowbase + r) << 3) + a) << 8) + c4;
    float4 v = *(const float4*)p;
    us4 hi = { f2bf(v.x), f2bf(v.y), f2bf(v.z), f2bf(v.w) };
    us4 lo = { f2bf(v.x - bf2f(hi[0])), f2bf(v.y - bf2f(hi[1])),
               f2bf(v.z - bf2f(hi[2])), f2bf(v.w - bf2f(hi[3])) };
    int idx = ((r << 8) + c4) ^ ((r & 7) << 3);   // XOR swizzle (16B blocks)
    *(us4*)(p0 + idx) = hi;
    *(us4*)(p1 + idx) = lo;
  }
}

// ------------- stage 32x256 f32 tile -> single bf16 plane, 256 thr ----------
static __device__ __forceinline__ void stage_single(unsigned short* p,
                                                    const float* __restrict__ src,
                                                    int rowbase, int a, int tid) {
#pragma unroll
  for (int k = 0; k < 8; ++k) {
    int j = tid + k * 256;
    int r = j >> 6;
    int c4 = (j & 63) << 2;
    const float* sp = src + ((((rowbase + r) << 3) + a) << 8) + c4;
    float4 v = *(const float4*)sp;
    us4 hi = { f2bf(v.x), f2bf(v.y), f2bf(v.z), f2bf(v.w) };
    int idx = ((r << 8) + c4) ^ ((r & 7) << 3);
    *(us4*)(p + idx) = hi;
  }
}

// ---- 32x64 GEMM over K=256, B from fragment layout (contiguous loads) ------
static __device__ __forceinline__ void mma64f(const unsigned short* lds,
                                              const unsigned short* __restrict__ wf,
                                              int cb0, int lane, int l16, int l4,
                                              f32x4 (&acc)[2][4]) {
#pragma unroll
  for (int ks = 0; ks < 8; ++ks) {
    s8 af[2], bw[4];
#pragma unroll
    for (int mt = 0; mt < 2; ++mt) {
      int row = mt * 16 + l16;
      int idx = ((row << 8) + ks * 32 + 8 * l4) ^ ((row & 7) << 3);
      af[mt] = *(const s8*)(lds + idx);
    }
#pragma unroll
    for (int nt = 0; nt < 4; ++nt)
      bw[nt] = *(const s8*)(wf + (cb0 + nt) * 4096 + ks * 512 + lane * 8);
#pragma unroll
    for (int mt = 0; mt < 2; ++mt)
#pragma unroll
      for (int nt = 0; nt < 4; ++nt)
        acc[mt][nt] = __builtin_amdgcn_mfma_f32_16x16x32_bf16(
            af[mt], bw[nt], acc[mt][nt], 0, 0, 0);
  }
}

// ---- 32x16 GEMM over K=256, fragment B (fallback kernel) -------------------
static __device__ __forceinline__ void mma16f(const unsigned short* lds,
                                              const unsigned short* __restrict__ wf,
                                              int cb, int lane, int l16, int l4,
                                              f32x4 (&acc)[2]) {
#pragma unroll
  for (int ks = 0; ks < 8; ++ks) {
    s8 bw = *(const s8*)(wf + cb * 4096 + ks * 512 + lane * 8);
#pragma unroll
    for (int mt = 0; mt < 2; ++mt) {
      int row = mt * 16 + l16;
      int idx = ((row << 8) + ks * 32 + 8 * l4) ^ ((row & 7) << 3);
      s8 af = *(const s8*)(lds + idx);
      acc[mt] = __builtin_amdgcn_mfma_f32_16x16x32_bf16(af, bw, acc[mt], 0, 0, 0);
    }
  }
}

// ====== K1: fc1 -> X fragments; h_in -> fragments; exact rowsums -> ws ======
__global__ __launch_bounds__(256, 2) void k1_fc1(
    const float* __restrict__ inp, const float* __restrict__ hin,
    const float* __restrict__ b1, unsigned short* __restrict__ ws) {
  __shared__ __align__(16) unsigned short P0[32 * 256];
  __shared__ __align__(16) unsigned short P1[32 * 256];
  __shared__ float RSXP[8][32], RSHP[8][32];
  const int tid = threadIdx.x;
  const int a = blockIdx.x & 7;
  const int rt = blockIdx.x >> 3;
  const int rowbase = rt * 32;
  const int lane = tid & 63, w = tid >> 6;
  const int l16 = lane & 15, l4 = lane >> 4;
  const int n0 = w * 64;

  stage_split(P0, P1, inp, rowbase, a, tid);
  __syncthreads();

  f32x4 XA[2][4];
#pragma unroll
  for (int mt = 0; mt < 2; ++mt)
#pragma unroll
    for (int nt = 0; nt < 4; ++nt) XA[mt][nt] = (f32x4){0.f, 0.f, 0.f, 0.f};
  mma64f(P0, ws + W1H_OFF + a * 65536, w * 4, lane, l16, l4, XA);
  mma64f(P1, ws + W1H_OFF + a * 65536, w * 4, lane, l16, l4, XA);
  mma64f(P0, ws + W1L_OFF + a * 65536, w * 4, lane, l16, l4, XA);
  __syncthreads();                           // all LDS reads done

  // write x bf16 -> P0 (swizzled); stage h_in bf16 -> P1 (swizzled)
#pragma unroll
  for (int nt = 0; nt < 4; ++nt) {
    int col = n0 + nt * 16 + l16;
    float bb = b1[a * 256 + col];
#pragma unroll
    for (int mt = 0; mt < 2; ++mt)
#pragma unroll
      for (int r = 0; r < 4; ++r) {
        float v = fmaxf(XA[mt][nt][r] + bb, 0.f);
        int row = mt * 16 + l4 * 4 + r;
        P0[((row << 8) + col) ^ ((row & 7) << 3)] = f2bf(v);
      }
  }
  stage_single(P1, hin, rowbase, a, tid);
  __syncthreads();

  // fragment-dump: P0 -> XF, P1 -> HF (contiguous us8 wave stores)
  const int rbg = (a << 8) + rt * 2;
#pragma unroll
  for (int i = 0; i < 4; ++i) {
    int c = tid + i * 256;                   // 0..1023 us8 chunks
    int rb = c >> 9, s = c & 511;            // s = ks*64 + l4*16 + l16
    int row = rb * 16 + (s & 15);
    int col = ((s >> 6) << 5) + (((s >> 4) & 3) << 3);
    int idx = ((row << 8) + col) ^ ((row & 7) << 3);
    *(us8*)(ws + XB_OFF + (rbg + rb) * 4096 + s * 8) = *(const us8*)(P0 + idx);
    *(us8*)(ws + HB_OFF + (rbg + rb) * 4096 + s * 8) = *(const us8*)(P1 + idx);
  }

  // exact f32 rowsums of the bf16 tiles -> ws (per-agent-row layout)
  {
    int row = tid >> 3, qd = tid & 7;
    float sx = 0.f, sh = 0.f;
#pragma unroll
    for (int i = 0; i < 8; ++i) {
      int c = qd * 32 + i * 4;
      int idx = ((row << 8) + c) ^ ((row & 7) << 3);
      us4 vx = *(const us4*)(P0 + idx);
      us4 vh = *(const us4*)(P1 + idx);
      sx += bf2f(vx[0]) + bf2f(vx[1]) + bf2f(vx[2]) + bf2f(vx[3]);
      sh += bf2f(vh[0]) + bf2f(vh[1]) + bf2f(vh[2]) + bf2f(vh[3]);
    }
    RSXP[qd][row] = sx; RSHP[qd][row] = sh;
  }
  __syncthreads();
  if (tid < 32) {
    float sx = 0.f, sh = 0.f;
#pragma unroll
    for (int qd = 0; qd < 8; ++qd) { sx += RSXP[qd][tid]; sh += RSHP[qd][tid]; }
    float* rsxg = (float*)(ws + RSX_U);
    float* rshg = (float*)(ws + RSH_U);
    rsxg[a * 4096 + rowbase + tid] = sx;
    rshg[a * 4096 + rowbase + tid] = sh;
  }
}

// ====== K2: mt=2 single-pass, LDS-staged A, rowsums from k1 =================
__global__ __launch_bounds__(256, 2) void k2_gates_nw(
    const float* __restrict__ hin, const float* __restrict__ bih,
    const float* __restrict__ bhh, const unsigned short* __restrict__ ws,
    float* __restrict__ out) {
  __shared__ __align__(16) unsigned short AX[2 * 4096];   // X fragments (16KB)
  __shared__ __align__(16) unsigned short AH[2 * 4096];   // H fragments (16KB)
  const int tid  = threadIdx.x;
  const int lane = tid & 63;
  const int w    = tid >> 6;
  const int bid  = blockIdx.x;
  const int a    = bid & 7;                 // agent == XCD
  const int g    = bid >> 3;
  const int rt   = g >> 1;                  // 32-row tile (slow)
  const int cs   = (g & 1) * 4 + w;         // col-slice 0..7
  const int rowbase = rt * 32;
  const int n0   = cs * 32;
  const int l16  = lane & 15, l4 = lane >> 4;

  // stage A fragments once per block (4 waves share the same 32 rows)
  {
    const unsigned short* XFg = ws + XB_OFF + ((a << 8) + rt * 2) * 4096;
    const unsigned short* HFg = ws + HB_OFF + ((a << 8) + rt * 2) * 4096;
#pragma unroll
    for (int i = 0; i < 4; ++i) {
      int c = tid + i * 256;                // 0..1023 us8 chunks
      *(us8*)(AX + c * 8) = *(const us8*)(XFg + c * 8);
      *(us8*)(AH + c * 8) = *(const us8*)(HFg + c * 8);
    }
  }
  __syncthreads();

  const unsigned short* WihR = ws + WIH_OFF + a * 196608 + (cs * 2) * 4096 + lane * 8;
  const unsigned short* WhhR = ws + WHH_OFF + a * 196608 + (cs * 2) * 4096 + lane * 8;

  f32x4 R[2][2], I[2][2], T[2][2], G[2][2];
#pragma unroll
  for (int mt = 0; mt < 2; ++mt)
#pragma unroll
    for (int nt = 0; nt < 2; ++nt) {
      R[mt][nt] = (f32x4){0.f, 0.f, 0.f, 0.f};
      I[mt][nt] = (f32x4){0.f, 0.f, 0.f, 0.f};
      T[mt][nt] = (f32x4){0.f, 0.f, 0.f, 0.f};
      G[mt][nt] = (f32x4){0.f, 0.f, 0.f, 0.f};
    }

  // ---- single pass: 4 LDS A-reads + 12 global B-loads + 24 MFMA per ks ----
#pragma unroll 2
  for (int ks = 0; ks < 8; ++ks) {
    const int ko = ks * 512 + lane * 8;
    s8 ax[2], ah[2];
#pragma unroll
    for (int mt = 0; mt < 2; ++mt) {
      ax[mt] = *(const s8*)(AX + mt * 4096 + ko);
      ah[mt] = *(const s8*)(AH + mt * 4096 + ko);
    }
    const int kg = ks * 512;
    s8 bxr[2], bhr[2], bxi[2], bhi[2], bxn[2], bhn[2];
#pragma unroll
    for (int nt = 0; nt < 2; ++nt) {
      bxr[nt] = *(const s8*)(WihR + nt * 4096 + kg);
      bhr[nt] = *(const s8*)(WhhR + nt * 4096 + kg);
      bxi[nt] = *(const s8*)(WihR + (16 + nt) * 4096 + kg);
      bhi[nt] = *(const s8*)(WhhR + (16 + nt) * 4096 + kg);
      bxn[nt] = *(const s8*)(WihR + (32 + nt) * 4096 + kg);
      bhn[nt] = *(const s8*)(WhhR + (32 + nt) * 4096 + kg);
    }
#pragma unroll
    for (int mt = 0; mt < 2; ++mt)
#pragma unroll
      for (int nt = 0; nt < 2; ++nt) {
        R[mt][nt] = __builtin_amdgcn_mfma_f32_16x16x32_bf16(ax[mt], bxr[nt], R[mt][nt], 0, 0, 0);
        R[mt][nt] = __builtin_amdgcn_mfma_f32_16x16x32_bf16(ah[mt], bhr[nt], R[mt][nt], 0, 0, 0);
        I[mt][nt] = __builtin_amdgcn_mfma_f32_16x16x32_bf16(ax[mt], bxi[nt], I[mt][nt], 0, 0, 0);
        I[mt][nt] = __builtin_amdgcn_mfma_f32_16x16x32_bf16(ah[mt], bhi[nt], I[mt][nt], 0, 0, 0);
        G[mt][nt] = __builtin_amdgcn_mfma_f32_16x16x32_bf16(ax[mt], bxn[nt], G[mt][nt], 0, 0, 0);
        T[mt][nt] = __builtin_amdgcn_mfma_f32_16x16x32_bf16(ah[mt], bhn[nt], T[mt][nt], 0, 0, 0);
      }
  }

  // ---- epilogue: rowsum broadcasts (from k1), gates, combine, store h ----
  const float* rsxg = (const float*)(ws + RSX_U) + a * 4096 + rowbase;
  const float* rshg = (const float*)(ws + RSH_U) + a * 4096 + rowbase;
#pragma unroll
  for (int mt = 0; mt < 2; ++mt) {
    float4 sx4 = *(const float4*)(rsxg + mt * 16 + l4 * 4);
    float4 sh4 = *(const float4*)(rshg + mt * 16 + l4 * 4);
    float rsx[4] = { sx4.x, sx4.y, sx4.z, sx4.w };
    float rsh[4] = { sh4.x, sh4.y, sh4.z, sh4.w };
#pragma unroll
    for (int nt = 0; nt < 2; ++nt) {
      int col = n0 + nt * 16 + l16;
      float br = bih[a * 768 + col] + bhh[a * 768 + col];
      float bi = bih[a * 768 + 256 + col] + bhh[a * 768 + 256 + col];
      float bnh = bhh[a * 768 + 512 + col];
      float bni = bih[a * 768 + 512 + col];
#pragma unroll
      for (int r = 0; r < 4; ++r) {
        float rg = sigm(R[mt][nt][r] + 0.5f * (rsx[r] + rsh[r]) + br);
        float t  = rg * (T[mt][nt][r] + 0.5f * rsh[r] + bnh);
        float ng = tanh_(G[mt][nt][r] + 0.5f * rsx[r] + bni + t);
        float ig = sigm(I[mt][nt][r] + 0.5f * (rsx[r] + rsh[r]) + bi);
        int row = mt * 16 + l4 * 4 + r;
        int flat = ((rowbase + row) << 3) + a;
        float hv = hin[(flat << 8) + col];
        out[QSIZE + (flat << 8) + col] = ng + ig * (hv - ng);
      }
    }
  }
}

// ========================== K3: fc2 -> q (out) ==============================
__global__ __launch_bounds__(128) void k3_fc2(
    const float* __restrict__ b2, const unsigned short* __restrict__ ws,
    float* __restrict__ out) {
  __shared__ __align__(16) unsigned short HB[32 * 256];
  const int tid = threadIdx.x;
  const int a = blockIdx.x & 7;
  const int rowbase = (blockIdx.x >> 3) * 32;
  const int lane = tid & 63, w = tid >> 6;
  const int l16 = lane & 15, l4 = lane >> 4;

#pragma unroll
  for (int k = 0; k < 16; ++k) {
    int j = tid + k * 128;
    int r = j >> 6;
    int c4 = (j & 63) << 2;
    const float* sp = out + QSIZE + ((((rowbase + r) << 3) + a) << 8) + c4;
    float4 v = *(const float4*)sp;
    us4 hi = { f2bf(v.x), f2bf(v.y), f2bf(v.z), f2bf(v.w) };
    int idx = ((r << 8) + c4) ^ ((r & 7) << 3);
    *(us4*)(HB + idx) = hi;
  }
  __syncthreads();

  f32x4 qa[2];
  qa[0] = (f32x4){0.f, 0.f, 0.f, 0.f};
  qa[1] = (f32x4){0.f, 0.f, 0.f, 0.f};
#pragma unroll
  for (int ks = 0; ks < 8; ++ks) {
    int row = w * 16 + l16;
    int idx = ((row << 8) + ks * 32 + 8 * l4) ^ ((row & 7) << 3);
    s8 af = *(const s8*)(HB + idx);
#pragma unroll
    for (int nt = 0; nt < 2; ++nt) {
      s8 bw = *(const s8*)(ws + W2T_OFF + a * 8192 + nt * 4096 + ks * 512 + lane * 8);
      qa[nt] = __builtin_amdgcn_mfma_f32_16x16x32_bf16(af, bw, qa[nt], 0, 0, 0);
    }
  }
#pragma unroll
  for (int nt = 0; nt < 2; ++nt) {
    int col = nt * 16 + l16;
    if (col < 30) {
      float bb = b2[a * 30 + col];
#pragma unroll
      for (int r = 0; r < 4; ++r) {
        int row = w * 16 + l4 * 4 + r;
        out[(((rowbase + row) << 3) + a) * 30 + col] = fmaxf(qa[nt][r] + bb, 0.f);
      }
    }
  }
}

// ======= fallback (ws too small for XF/HF): fused kernel, fragment W ========
__global__ __launch_bounds__(256, 2) void fused_agent_rnn(
    const float* __restrict__ inp,  const float* __restrict__ hin,
    const float* __restrict__ b1,   const float* __restrict__ bih,
    const float* __restrict__ bhh,  const float* __restrict__ b2,
    const unsigned short* __restrict__ ws, float* __restrict__ out) {
  __shared__ __align__(16) unsigned short P0[32 * 256];
  __shared__ __align__(16) unsigned short P1[32 * 256];
  __shared__ float RSXP[8][32], RSHP[8][32];
  __shared__ float RSX[32], RSH[32];

  const int tid = threadIdx.x;
  const int a = blockIdx.x & 7;
  const int rowbase = (blockIdx.x >> 3) * 32;
  const int lane = tid & 63, w = tid >> 6;
  const int l16 = lane & 15, l4 = lane >> 4;
  const int n0 = w * 64;

  stage_split(P0, P1, inp, rowbase, a, tid);
  __syncthreads();
  {
    f32x4 XA[2][4];
#pragma unroll
    for (int mt = 0; mt < 2; ++mt)
#pragma unroll
      for (int nt = 0; nt < 4; ++nt) XA[mt][nt] = (f32x4){0.f, 0.f, 0.f, 0.f};
    mma64f(P0, ws + W1H_OFF + a * 65536, w * 4, lane, l16, l4, XA);
    mma64f(P1, ws + W1H_OFF + a * 65536, w * 4, lane, l16, l4, XA);
    mma64f(P0, ws + W1L_OFF + a * 65536, w * 4, lane, l16, l4, XA);
    __syncthreads();
#pragma unroll
    for (int nt = 0; nt < 4; ++nt) {
      int col = n0 + nt * 16 + l16;
      float bb = b1[a * 256 + col];
#pragma unroll
      for (int mt = 0; mt < 2; ++mt)
#pragma unroll
        for (int r = 0; r < 4; ++r) {
          float v = fmaxf(XA[mt][nt][r] + bb, 0.f);
          int row = mt * 16 + l4 * 4 + r;
          P0[((row << 8) + col) ^ ((row & 7) << 3)] = f2bf(v);
        }
    }
  }
  stage_single(P1, hin, rowbase, a, tid);
  __syncthreads();
  {
    int row = tid >> 3, qd = tid & 7;
    float sx = 0.f, sh = 0.f;
#pragma unroll
    for (int i = 0; i < 8; ++i) {
      int c = qd * 32 + i * 4;
      int idx = ((row << 8) + c) ^ ((row & 7) << 3);
      us4 vx = *(const us4*)(P0 + idx);
      us4 vh = *(const us4*)(P1 + idx);
      sx += bf2f(vx[0]) + bf2f(vx[1]) + bf2f(vx[2]) + bf2f(vx[3]);
      sh += bf2f(vh[0]) + bf2f(vh[1]) + bf2f(vh[2]) + bf2f(vh[3]);
    }
    RSXP[qd][row] = sx; RSHP[qd][row] = sh;
  }
  __syncthreads();
  if (tid < 32) {
    float sx = 0.f, sh = 0.f;
#pragma unroll
    for (int qd = 0; qd < 8; ++qd) { sx += RSXP[qd][tid]; sh += RSHP[qd][tid]; }
    RSX[tid] = sx; RSH[tid] = sh;
  }
  __syncthreads();

  const unsigned short* WihF = ws + WIH_OFF + a * 196608;
  const unsigned short* WhhF = ws + WHH_OFF + a * 196608;

  for (int nt = 0; nt < 4; ++nt) {
    const int col = n0 + nt * 16 + l16;
    const int cb = w * 4 + nt;               // gate-local col-block
    f32x4 R4[2], T4[2], G4[2];
#pragma unroll
    for (int mt = 0; mt < 2; ++mt) R4[mt] = (f32x4){0.f, 0.f, 0.f, 0.f};
    mma16f(P0, WihF, cb, lane, l16, l4, R4);
    mma16f(P1, WhhF, cb, lane, l16, l4, R4);
    {
      float bb = bih[a * 768 + col] + bhh[a * 768 + col];
#pragma unroll
      for (int mt = 0; mt < 2; ++mt)
#pragma unroll
        for (int r = 0; r < 4; ++r) {
          int row = mt * 16 + l4 * 4 + r;
          R4[mt][r] = sigm(R4[mt][r] + 0.5f * (RSX[row] + RSH[row]) + bb);
        }
    }
#pragma unroll
    for (int mt = 0; mt < 2; ++mt) T4[mt] = (f32x4){0.f, 0.f, 0.f, 0.f};
    mma16f(P1, WhhF, 32 + cb, lane, l16, l4, T4);
    {
      float bb = bhh[a * 768 + 512 + col];
#pragma unroll
      for (int mt = 0; mt < 2; ++mt)
#pragma unroll
        for (int r = 0; r < 4; ++r) {
          int row = mt * 16 + l4 * 4 + r;
          T4[mt][r] = R4[mt][r] * (T4[mt][r] + 0.5f * RSH[row] + bb);
        }
    }
#pragma unroll
    for (int mt = 0; mt < 2; ++mt) G4[mt] = (f32x4){0.f, 0.f, 0.f, 0.f};
    mma16f(P0, WihF, 32 + cb, lane, l16, l4, G4);
    {
      float bb = bih[a * 768 + 512 + col];
#pragma unroll
      for (int mt = 0; mt < 2; ++mt)
#pragma unroll
        for (int r = 0; r < 4; ++r) {
          int row = mt * 16 + l4 * 4 + r;
          T4[mt][r] = tanh_(G4[mt][r] + 0.5f * RSX[row] + bb + T4[mt][r]);
        }
    }
#pragma unroll
    for (int mt = 0; mt < 2; ++mt) G4[mt] = (f32x4){0.f, 0.f, 0.f, 0.f};
    mma16f(P0, WihF, 16 + cb, lane, l16, l4, G4);
    mma16f(P1, WhhF, 16 + cb, lane, l16, l4, G4);
    {
      float bb = bih[a * 768 + 256 + col] + bhh[a * 768 + 256 + col];
#pragma unroll
      for (int mt = 0; mt < 2; ++mt)
#pragma unroll
        for (int r = 0; r < 4; ++r) {
          int row = mt * 16 + l4 * 4 + r;
          float ig = sigm(G4[mt][r] + 0.5f * (RSX[row] + RSH[row]) + bb);
          float hv = bf2f(P1[((row << 8) + col) ^ ((row & 7) << 3)]);
          float ng = T4[mt][r];
          out[QSIZE + ((((rowbase + row) << 3) + a) << 8) + col]
              = ng + ig * (hv - ng);
        }
    }
  }
  __syncthreads();
  stage_single(P0, out + QSIZE, rowbase, a, tid);
  __syncthreads();
  if (w < 2) {
    f32x4 qa[2];
    qa[0] = (f32x4){0.f, 0.f, 0.f, 0.f};
    qa[1] = (f32x4){0.f, 0.f, 0.f, 0.f};
#pragma unroll
    for (int ks = 0; ks < 8; ++ks) {
      int row = w * 16 + l16;
      int idx = ((row << 8) + ks * 32 + 8 * l4) ^ ((row & 7) << 3);
      s8 af = *(const s8*)(P0 + idx);
#pragma unroll
      for (int nt = 0; nt < 2; ++nt) {
        s8 bw = *(const s8*)(ws + W2T_OFF + a * 8192 + nt * 4096 + ks * 512 + lane * 8);
        qa[nt] = __builtin_amdgcn_mfma_f32_16x16x32_bf16(af, bw, qa[nt], 0, 0, 0);
      }
    }
#pragma unroll
    for (int nt = 0; nt < 2; ++nt) {
      int col = nt * 16 + l16;
      if (col < 30) {
        float bb = b2[a * 30 + col];
#pragma unroll
        for (int r = 0; r < 4; ++r) {
          int row = w * 16 + l4 * 4 + r;
          out[(((rowbase + row) << 3) + a) * 30 + col] = fmaxf(qa[nt][r] + bb, 0.f);
        }
      }
    }
  }
}

extern "C" void kernel_launch(void* const* d_in, const int* in_sizes, int n_in,
                              void* d_out, int out_size, void* d_ws, size_t ws_size,
                              hipStream_t stream) {
  const float* inputs = (const float*)d_in[0];
  const float* hidden = (const float*)d_in[1];
  const float* fc1w   = (const float*)d_in[2];
  const float* fc1b   = (const float*)d_in[3];
  const float* rihw   = (const float*)d_in[4];
  const float* rihb   = (const float*)d_in[5];
  const float* rhhw   = (const float*)d_in[6];
  const float* rhhb   = (const float*)d_in[7];
  const float* fc2w   = (const float*)d_in[8];
  const float* fc2b   = (const float*)d_in[9];
  unsigned short* ws  = (unsigned short*)d_ws;
  float* out          = (float*)d_out;

  hipLaunchKernelGGL(prep_weights, dim3(3648), dim3(256), 0, stream,
                     fc1w, rihw, rhhw, fc2w, ws);

  if (ws_size >= WS_NEED_NEW) {
    hipLaunchKernelGGL(k1_fc1, dim3(1024), dim3(256), 0, stream,
                       inputs, hidden, fc1b, ws);
    hipLaunchKernelGGL(k2_gates_nw, dim3(2048), dim3(256), 0, stream,
                       hidden, rihb, rhhb, ws, out);
    hipLaunchKernelGGL(k3_fc2, dim3(1024), dim3(128), 0, stream, fc2b, ws, out);
  } else {
    hipLaunchKernelGGL(fused_agent_rnn, dim3(1024), dim3(256), 0, stream,
                       inputs, hidden, fc1b, rihb, rhhb, fc2b, ws, out);
  }
}

// Round 14
// 95.148 us; speedup vs baseline: 1.4005x; 1.0903x over previous
//
#include <hip/hip_runtime.h>

// ---------------------------------------------------------------------------
// LatentMixtureAllRNNAgent: per-agent fc1 -> GRU cell -> fc2 on MI355X.
// Round 14: structural trim. (a) fc2 folded into k2 (512-thr blocks, 8 waves
// = all 8 col-slices of one 32-row tile; h -> LDS; waves 0-1 run fc2) — k3
// eliminated with its 33.5MB h re-read. (b) hv for the GRU combine read from
// the AH LDS fragments (bf16, proven rounds 2-9) — removes k2's 33.5MB f32
// hin read. (c) k1 fc1 passes fused into one ks-loop sharing the W1H load
// (12 -> 8 global loads/ks). Gate math/operands identical (absmax 1.0).
// Residency: k2 regs ~128 total (64 VGPR + 64 AGPR), LDS 32KB.
// ---------------------------------------------------------------------------

typedef __attribute__((ext_vector_type(4))) float f32x4;
typedef __attribute__((ext_vector_type(8))) short s8;     // 8 bf16 (4 VGPRs)
typedef __attribute__((ext_vector_type(4))) unsigned short us4;
typedef __attribute__((ext_vector_type(8))) unsigned short us8;

#define QSIZE   983040      /* 32768*30 */
#define W1H_OFF 0
#define W1L_OFF 524288
#define WIH_OFF 1048576
#define WHH_OFF 2621440
#define W2T_OFF 4194304
#define XB_OFF  4259840                 /* X fragments:   8a x 256rb x 4096 */
#define HB_OFF  12648448                /* h_in fragments: same */
#define RSX_U   21037056                /* f32 rowsum(x):   8a x 4096 rows  */
#define RSH_U   21102592                /* f32 rowsum(h_in): same           */
#define WS_NEED_NEW 42336256ull        /* bytes */

static __device__ __forceinline__ unsigned short f2bf(float f) {
  union { float f; unsigned u; } v; v.f = f;
  unsigned r = v.u + 0x7FFFu + ((v.u >> 16) & 1u);   // RNE
  return (unsigned short)(r >> 16);
}
static __device__ __forceinline__ float bf2f(unsigned short u) {
  union { unsigned u; float f; } v; v.u = ((unsigned)u) << 16;
  return v.f;
}
static __device__ __forceinline__ float sigm(float x) {
  return 1.0f / (1.0f + __expf(-x));
}
static __device__ __forceinline__ float tanh_(float x) {
  return 1.0f - 2.0f / (__expf(2.0f * x) + 1.0f);
}

// ---- prep: f32 [a][k][n] -> bf16 fragment layout [a][cb][ks][l4][l16][8] ---
__global__ void prep_weights(const float* __restrict__ fc1w,
                             const float* __restrict__ rihw,
                             const float* __restrict__ rhhw,
                             const float* __restrict__ fc2w,
                             unsigned short* __restrict__ ws) {
  int q = blockIdx.x * 256 + threadIdx.x;   // one us4 (4 k-values) per thread
  if (q < 131072) {                         // fc1: hi + lo, 8a x 16cb x 1024
    int a = q >> 14, rem = q & 16383;
    int cb = rem >> 10, s = rem & 1023;
    int ks = s >> 7, l4 = (s >> 5) & 3, l16 = (s >> 1) & 15, hf = s & 1;
    int n = cb * 16 + l16, k0 = ks * 32 + l4 * 8 + hf * 4;
    const float* sp = fc1w + a * 65536 + k0 * 256 + n;
    float v0 = sp[0], v1 = sp[256], v2 = sp[512], v3 = sp[768];
    us4 hi = { f2bf(v0), f2bf(v1), f2bf(v2), f2bf(v3) };
    us4 lo = { f2bf(v0 - bf2f(hi[0])), f2bf(v1 - bf2f(hi[1])),
               f2bf(v2 - bf2f(hi[2])), f2bf(v3 - bf2f(hi[3])) };
    int o = a * 65536 + cb * 4096 + ks * 512 + l4 * 128 + l16 * 8 + hf * 4;
    *(us4*)(ws + W1H_OFF + o) = hi;
    *(us4*)(ws + W1L_OFF + o) = lo;
  } else if (q < 524288) {                  // rnn_ih centered: 8a x 48cb
    int t = q - 131072;
    int a = t / 49152, rem = t % 49152;
    int cb = rem >> 10, s = rem & 1023;
    int ks = s >> 7, l4 = (s >> 5) & 3, l16 = (s >> 1) & 15, hf = s & 1;
    int n = cb * 16 + l16, k0 = ks * 32 + l4 * 8 + hf * 4;
    const float* sp = rihw + a * 196608 + k0 * 768 + n;
    us4 v = { f2bf(sp[0] - 0.5f), f2bf(sp[768] - 0.5f),
              f2bf(sp[1536] - 0.5f), f2bf(sp[2304] - 0.5f) };
    *(us4*)(ws + WIH_OFF + a * 196608 + cb * 4096 + ks * 512 + l4 * 128
            + l16 * 8 + hf * 4) = v;
  } else if (q < 917504) {                  // rnn_hh centered
    int t = q - 524288;
    int a = t / 49152, rem = t % 49152;
    int cb = rem >> 10, s = rem & 1023;
    int ks = s >> 7, l4 = (s >> 5) & 3, l16 = (s >> 1) & 15, hf = s & 1;
    int n = cb * 16 + l16, k0 = ks * 32 + l4 * 8 + hf * 4;
    const float* sp = rhhw + a * 196608 + k0 * 768 + n;
    us4 v = { f2bf(sp[0] - 0.5f), f2bf(sp[768] - 0.5f),
              f2bf(sp[1536] - 0.5f), f2bf(sp[2304] - 0.5f) };
    *(us4*)(ws + WHH_OFF + a * 196608 + cb * 4096 + ks * 512 + l4 * 128
            + l16 * 8 + hf * 4) = v;
  } else if (q < 933888) {                  // fc2: 8a x 2cb, pad n>=30 -> 0
    int t = q - 917504;
    int a = t >> 11, rem = t & 2047;
    int cb = rem >> 10, s = rem & 1023;
    int ks = s >> 7, l4 = (s >> 5) & 3, l16 = (s >> 1) & 15, hf = s & 1;
    int n = cb * 16 + l16, k0 = ks * 32 + l4 * 8 + hf * 4;
    us4 v = { 0, 0, 0, 0 };
    if (n < 30) {
      const float* sp = fc2w + a * 7680 + k0 * 30 + n;
      v = (us4){ f2bf(sp[0]), f2bf(sp[30]), f2bf(sp[60]), f2bf(sp[90]) };
    }
    *(us4*)(ws + W2T_OFF + a * 8192 + cb * 4096 + ks * 512 + l4 * 128
            + l16 * 8 + hf * 4) = v;
  }
}

// ------- stage 32x256 f32 tile -> split bf16 (hi p0, lo p1), 256 thr --------
static __device__ __forceinline__ void stage_split(unsigned short* p0,
                                                   unsigned short* p1,
                                                   const float* __restrict__ src,
                                                   int rowbase, int a, int tid) {
#pragma unroll
  for (int k = 0; k < 8; ++k) {
    int j = tid + k * 256;
    int r = j >> 6;
    int c4 = (j & 63) << 2;
    const float* p = src + ((((rowbase + r) << 3) + a) << 8) + c4;
    float4 v = *(const float4*)p;
    us4 hi = { f2bf(v.x), f2bf(v.y), f2bf(v.z), f2bf(v.w) };
    us4 lo = { f2bf(v.x - bf2f(hi[0])), f2bf(v.y - bf2f(hi[1])),
               f2bf(v.z - bf2f(hi[2])), f2bf(v.w - bf2f(hi[3])) };
    int idx = ((r << 8) + c4) ^ ((r & 7) << 3);   // XOR swizzle (16B blocks)
    *(us4*)(p0 + idx) = hi;
    *(us4*)(p1 + idx) = lo;
  }
}

// ------------- stage 32x256 f32 tile -> single bf16 plane, 256 thr ----------
static __device__ __forceinline__ void stage_single(unsigned short* p,
                                                    const float* __restrict__ src,
                                                    int rowbase, int a, int tid) {
#pragma unroll
  for (int k = 0; k < 8; ++k) {
    int j = tid + k * 256;
    int r = j >> 6;
    int c4 = (j & 63) << 2;
    const float* sp = src + ((((rowbase + r) << 3) + a) << 8) + c4;
    float4 v = *(const float4*)sp;
    us4 hi = { f2bf(v.x), f2bf(v.y), f2bf(v.z), f2bf(v.w) };
    int idx = ((r << 8) + c4) ^ ((r & 7) << 3);
    *(us4*)(p + idx) = hi;
  }
}

// ---- 32x64 GEMM over K=256, B from fragment layout (fallback only) ---------
static __device__ __forceinline__ void mma64f(const unsigned short* lds,
                                              const unsigned short* __restrict__ wf,
                                              int cb0, int lane, int l16, int l4,
                                              f32x4 (&acc)[2][4]) {
#pragma unroll
  for (int ks = 0; ks < 8; ++ks) {
    s8 af[2], bw[4];
#pragma unroll
    for (int mt = 0; mt < 2; ++mt) {
      int row = mt * 16 + l16;
      int idx = ((row << 8) + ks * 32 + 8 * l4) ^ ((row & 7) << 3);
      af[mt] = *(const s8*)(lds + idx);
    }
#pragma unroll
    for (int nt = 0; nt < 4; ++nt)
      bw[nt] = *(const s8*)(wf + (cb0 + nt) * 4096 + ks * 512 + lane * 8);
#pragma unroll
    for (int mt = 0; mt < 2; ++mt)
#pragma unroll
      for (int nt = 0; nt < 4; ++nt)
        acc[mt][nt] = __builtin_amdgcn_mfma_f32_16x16x32_bf16(
            af[mt], bw[nt], acc[mt][nt], 0, 0, 0);
  }
}

// ---- 32x16 GEMM over K=256, fragment B (fallback kernel) -------------------
static __device__ __forceinline__ void mma16f(const unsigned short* lds,
                                              const unsigned short* __restrict__ wf,
                                              int cb, int lane, int l16, int l4,
                                              f32x4 (&acc)[2]) {
#pragma unroll
  for (int ks = 0; ks < 8; ++ks) {
    s8 bw = *(const s8*)(wf + cb * 4096 + ks * 512 + lane * 8);
#pragma unroll
    for (int mt = 0; mt < 2; ++mt) {
      int row = mt * 16 + l16;
      int idx = ((row << 8) + ks * 32 + 8 * l4) ^ ((row & 7) << 3);
      s8 af = *(const s8*)(lds + idx);
      acc[mt] = __builtin_amdgcn_mfma_f32_16x16x32_bf16(af, bw, acc[mt], 0, 0, 0);
    }
  }
}

// ====== K1: fc1 (fused 3-pass) -> X fragments; h_in frags; rowsums ==========
__global__ __launch_bounds__(256, 2) void k1_fc1(
    const float* __restrict__ inp, const float* __restrict__ hin,
    const float* __restrict__ b1, unsigned short* __restrict__ ws) {
  __shared__ __align__(16) unsigned short P0[32 * 256];
  __shared__ __align__(16) unsigned short P1[32 * 256];
  __shared__ float RSXP[8][32], RSHP[8][32];
  const int tid = threadIdx.x;
  const int a = blockIdx.x & 7;
  const int rt = blockIdx.x >> 3;
  const int rowbase = rt * 32;
  const int lane = tid & 63, w = tid >> 6;
  const int l16 = lane & 15, l4 = lane >> 4;
  const int n0 = w * 64;

  stage_split(P0, P1, inp, rowbase, a, tid);
  __syncthreads();

  f32x4 XA[2][4];
#pragma unroll
  for (int mt = 0; mt < 2; ++mt)
#pragma unroll
    for (int nt = 0; nt < 4; ++nt) XA[mt][nt] = (f32x4){0.f, 0.f, 0.f, 0.f};

  {  // fused: per ks load W1H once (feeds P0 and P1 passes) + W1L
    const unsigned short* WH = ws + W1H_OFF + a * 65536 + (w * 4) * 4096 + lane * 8;
    const unsigned short* WL = ws + W1L_OFF + a * 65536 + (w * 4) * 4096 + lane * 8;
#pragma unroll 2
    for (int ks = 0; ks < 8; ++ks) {
      s8 af0[2], af1[2];
#pragma unroll
      for (int mt = 0; mt < 2; ++mt) {
        int row = mt * 16 + l16;
        int idx = ((row << 8) + ks * 32 + 8 * l4) ^ ((row & 7) << 3);
        af0[mt] = *(const s8*)(P0 + idx);
        af1[mt] = *(const s8*)(P1 + idx);
      }
      s8 bh[4], bl[4];
#pragma unroll
      for (int nt = 0; nt < 4; ++nt) {
        bh[nt] = *(const s8*)(WH + nt * 4096 + ks * 512);
        bl[nt] = *(const s8*)(WL + nt * 4096 + ks * 512);
      }
#pragma unroll
      for (int mt = 0; mt < 2; ++mt)
#pragma unroll
        for (int nt = 0; nt < 4; ++nt) {
          XA[mt][nt] = __builtin_amdgcn_mfma_f32_16x16x32_bf16(af0[mt], bh[nt], XA[mt][nt], 0, 0, 0);
          XA[mt][nt] = __builtin_amdgcn_mfma_f32_16x16x32_bf16(af1[mt], bh[nt], XA[mt][nt], 0, 0, 0);
          XA[mt][nt] = __builtin_amdgcn_mfma_f32_16x16x32_bf16(af0[mt], bl[nt], XA[mt][nt], 0, 0, 0);
        }
    }
  }
  __syncthreads();                           // all LDS reads done

  // write x bf16 -> P0 (swizzled); stage h_in bf16 -> P1 (swizzled)
#pragma unroll
  for (int nt = 0; nt < 4; ++nt) {
    int col = n0 + nt * 16 + l16;
    float bb = b1[a * 256 + col];
#pragma unroll
    for (int mt = 0; mt < 2; ++mt)
#pragma unroll
      for (int r = 0; r < 4; ++r) {
        float v = fmaxf(XA[mt][nt][r] + bb, 0.f);
        int row = mt * 16 + l4 * 4 + r;
        P0[((row << 8) + col) ^ ((row & 7) << 3)] = f2bf(v);
      }
  }
  stage_single(P1, hin, rowbase, a, tid);
  __syncthreads();

  // fragment-dump: P0 -> XF, P1 -> HF (contiguous us8 wave stores)
  const int rbg = (a << 8) + rt * 2;
#pragma unroll
  for (int i = 0; i < 4; ++i) {
    int c = tid + i * 256;                   // 0..1023 us8 chunks
    int rb = c >> 9, s = c & 511;            // s = ks*64 + l4*16 + l16
    int row = rb * 16 + (s & 15);
    int col = ((s >> 6) << 5) + (((s >> 4) & 3) << 3);
    int idx = ((row << 8) + col) ^ ((row & 7) << 3);
    *(us8*)(ws + XB_OFF + (rbg + rb) * 4096 + s * 8) = *(const us8*)(P0 + idx);
    *(us8*)(ws + HB_OFF + (rbg + rb) * 4096 + s * 8) = *(const us8*)(P1 + idx);
  }

  // exact f32 rowsums of the bf16 tiles -> ws (per-agent-row layout)
  {
    int row = tid >> 3, qd = tid & 7;
    float sx = 0.f, sh = 0.f;
#pragma unroll
    for (int i = 0; i < 8; ++i) {
      int c = qd * 32 + i * 4;
      int idx = ((row << 8) + c) ^ ((row & 7) << 3);
      us4 vx = *(const us4*)(P0 + idx);
      us4 vh = *(const us4*)(P1 + idx);
      sx += bf2f(vx[0]) + bf2f(vx[1]) + bf2f(vx[2]) + bf2f(vx[3]);
      sh += bf2f(vh[0]) + bf2f(vh[1]) + bf2f(vh[2]) + bf2f(vh[3]);
    }
    RSXP[qd][row] = sx; RSHP[qd][row] = sh;
  }
  __syncthreads();
  if (tid < 32) {
    float sx = 0.f, sh = 0.f;
#pragma unroll
    for (int qd = 0; qd < 8; ++qd) { sx += RSXP[qd][tid]; sh += RSHP[qd][tid]; }
    float* rsxg = (float*)(ws + RSX_U);
    float* rshg = (float*)(ws + RSH_U);
    rsxg[a * 4096 + rowbase + tid] = sx;
    rshg[a * 4096 + rowbase + tid] = sh;
  }
}

// ====== K2 fused: gates (8 waves = 8 col-slices) + fc2 tail =================
__global__ __launch_bounds__(512, 3) void k2_fused(
    const float* __restrict__ bih, const float* __restrict__ bhh,
    const float* __restrict__ b2, const unsigned short* __restrict__ ws,
    float* __restrict__ out) {
  __shared__ __align__(16) unsigned short AX[8192];   // X frags -> h bf16 (16KB)
  __shared__ __align__(16) unsigned short AH[8192];   // H frags (16KB)
  const int tid  = threadIdx.x;
  const int lane = tid & 63;
  const int w    = tid >> 6;                // 0..7 = col-slice
  const int a    = blockIdx.x & 7;          // agent == XCD
  const int rt   = blockIdx.x >> 3;         // 0..127
  const int rowbase = rt * 32;
  const int cs   = w;
  const int n0   = cs * 32;
  const int l16  = lane & 15, qr = lane >> 4;

  // stage A fragments once per block (all 8 waves share the same 32 rows)
  {
    const unsigned short* XFg = ws + XB_OFF + ((a << 8) + rt * 2) * 4096;
    const unsigned short* HFg = ws + HB_OFF + ((a << 8) + rt * 2) * 4096;
#pragma unroll
    for (int i = 0; i < 2; ++i) {
      int c = tid + i * 512;                // 0..1023 us8 chunks
      *(us8*)(AX + c * 8) = *(const us8*)(XFg + c * 8);
      *(us8*)(AH + c * 8) = *(const us8*)(HFg + c * 8);
    }
  }
  __syncthreads();

  const unsigned short* WihR = ws + WIH_OFF + a * 196608 + (cs * 2) * 4096 + lane * 8;
  const unsigned short* WhhR = ws + WHH_OFF + a * 196608 + (cs * 2) * 4096 + lane * 8;

  f32x4 R[2][2], I[2][2], T[2][2], G[2][2];
#pragma unroll
  for (int mt = 0; mt < 2; ++mt)
#pragma unroll
    for (int nt = 0; nt < 2; ++nt) {
      R[mt][nt] = (f32x4){0.f, 0.f, 0.f, 0.f};
      I[mt][nt] = (f32x4){0.f, 0.f, 0.f, 0.f};
      T[mt][nt] = (f32x4){0.f, 0.f, 0.f, 0.f};
      G[mt][nt] = (f32x4){0.f, 0.f, 0.f, 0.f};
    }

  // ---- single pass: 4 LDS A-reads + 12 global B-loads + 24 MFMA per ks ----
#pragma unroll 2
  for (int ks = 0; ks < 8; ++ks) {
    const int ko = ks * 512 + lane * 8;
    s8 ax[2], ah[2];
#pragma unroll
    for (int mt = 0; mt < 2; ++mt) {
      ax[mt] = *(const s8*)(AX + mt * 4096 + ko);
      ah[mt] = *(const s8*)(AH + mt * 4096 + ko);
    }
    const int kg = ks * 512;
    s8 bxr[2], bhr[2], bxi[2], bhi[2], bxn[2], bhn[2];
#pragma unroll
    for (int nt = 0; nt < 2; ++nt) {
      bxr[nt] = *(const s8*)(WihR + nt * 4096 + kg);
      bhr[nt] = *(const s8*)(WhhR + nt * 4096 + kg);
      bxi[nt] = *(const s8*)(WihR + (16 + nt) * 4096 + kg);
      bhi[nt] = *(const s8*)(WhhR + (16 + nt) * 4096 + kg);
      bxn[nt] = *(const s8*)(WihR + (32 + nt) * 4096 + kg);
      bhn[nt] = *(const s8*)(WhhR + (32 + nt) * 4096 + kg);
    }
#pragma unroll
    for (int mt = 0; mt < 2; ++mt)
#pragma unroll
      for (int nt = 0; nt < 2; ++nt) {
        R[mt][nt] = __builtin_amdgcn_mfma_f32_16x16x32_bf16(ax[mt], bxr[nt], R[mt][nt], 0, 0, 0);
        R[mt][nt] = __builtin_amdgcn_mfma_f32_16x16x32_bf16(ah[mt], bhr[nt], R[mt][nt], 0, 0, 0);
        I[mt][nt] = __builtin_amdgcn_mfma_f32_16x16x32_bf16(ax[mt], bxi[nt], I[mt][nt], 0, 0, 0);
        I[mt][nt] = __builtin_amdgcn_mfma_f32_16x16x32_bf16(ah[mt], bhi[nt], I[mt][nt], 0, 0, 0);
        G[mt][nt] = __builtin_amdgcn_mfma_f32_16x16x32_bf16(ax[mt], bxn[nt], G[mt][nt], 0, 0, 0);
        T[mt][nt] = __builtin_amdgcn_mfma_f32_16x16x32_bf16(ah[mt], bhn[nt], T[mt][nt], 0, 0, 0);
      }
  }

  // ---- epilogue: gates, combine (hv from AH bf16), store h, keep local ----
  const float* rsxg = (const float*)(ws + RSX_U) + a * 4096 + rowbase;
  const float* rshg = (const float*)(ws + RSH_U) + a * 4096 + rowbase;
  float hloc[2][2][4];
#pragma unroll
  for (int mt = 0; mt < 2; ++mt) {
    float4 sx4 = *(const float4*)(rsxg + mt * 16 + qr * 4);
    float4 sh4 = *(const float4*)(rshg + mt * 16 + qr * 4);
    float rsx[4] = { sx4.x, sx4.y, sx4.z, sx4.w };
    float rsh[4] = { sh4.x, sh4.y, sh4.z, sh4.w };
#pragma unroll
    for (int nt = 0; nt < 2; ++nt) {
      int col = n0 + nt * 16 + l16;
      float br = bih[a * 768 + col] + bhh[a * 768 + col];
      float bi = bih[a * 768 + 256 + col] + bhh[a * 768 + 256 + col];
      float bnh = bhh[a * 768 + 512 + col];
      float bni = bih[a * 768 + 512 + col];
#pragma unroll
      for (int r = 0; r < 4; ++r) {
        float rg = sigm(R[mt][nt][r] + 0.5f * (rsx[r] + rsh[r]) + br);
        float t  = rg * (T[mt][nt][r] + 0.5f * rsh[r] + bnh);
        float ng = tanh_(G[mt][nt][r] + 0.5f * rsx[r] + bni + t);
        float ig = sigm(I[mt][nt][r] + 0.5f * (rsx[r] + rsh[r]) + bi);
        int row = mt * 16 + qr * 4 + r;
        int flat = ((rowbase + row) << 3) + a;
        int hidx = mt * 4096 + cs * 512 + (nt * 2 + (l16 >> 3)) * 128
                 + (qr * 4 + r) * 8 + (l16 & 7);
        float hv = bf2f(AH[hidx]);
        float h = ng + ig * (hv - ng);
        out[QSIZE + (flat << 8) + col] = h;
        hloc[mt][nt][r] = h;
      }
    }
  }
  __syncthreads();   // all gate-loop AX reads complete

  // write h bf16 -> AX (swizzled 32x256 row-major) for fc2
#pragma unroll
  for (int mt = 0; mt < 2; ++mt)
#pragma unroll
    for (int nt = 0; nt < 2; ++nt)
#pragma unroll
      for (int r = 0; r < 4; ++r) {
        int row = mt * 16 + qr * 4 + r;
        int col = n0 + nt * 16 + l16;
        AX[((row << 8) + col) ^ ((row & 7) << 3)] = f2bf(hloc[mt][nt][r]);
      }
  __syncthreads();

  // ---- fc2 tail: waves 0-1, 16 rows each (k3's proven body) ----
  if (w < 2) {
    f32x4 qa[2];
    qa[0] = (f32x4){0.f, 0.f, 0.f, 0.f};
    qa[1] = (f32x4){0.f, 0.f, 0.f, 0.f};
#pragma unroll
    for (int ks = 0; ks < 8; ++ks) {
      int row = w * 16 + l16;
      int idx = ((row << 8) + ks * 32 + 8 * qr) ^ ((row & 7) << 3);
      s8 af = *(const s8*)(AX + idx);
#pragma unroll
      for (int nt = 0; nt < 2; ++nt) {
        s8 bw = *(const s8*)(ws + W2T_OFF + a * 8192 + nt * 4096 + ks * 512 + lane * 8);
        qa[nt] = __builtin_amdgcn_mfma_f32_16x16x32_bf16(af, bw, qa[nt], 0, 0, 0);
      }
    }
#pragma unroll
    for (int nt = 0; nt < 2; ++nt) {
      int col = nt * 16 + l16;
      if (col < 30) {
        float bb = b2[a * 30 + col];
#pragma unroll
        for (int r = 0; r < 4; ++r) {
          int row = w * 16 + qr * 4 + r;
          out[(((rowbase + row) << 3) + a) * 30 + col] = fmaxf(qa[nt][r] + bb, 0.f);
        }
      }
    }
  }
}

// ======= fallback (ws too small for XF/HF): fused kernel, fragment W ========
__global__ __launch_bounds__(256, 2) void fused_agent_rnn(
    const float* __restrict__ inp,  const float* __restrict__ hin,
    const float* __restrict__ b1,   const float* __restrict__ bih,
    const float* __restrict__ bhh,  const float* __restrict__ b2,
    const unsigned short* __restrict__ ws, float* __restrict__ out) {
  __shared__ __align__(16) unsigned short P0[32 * 256];
  __shared__ __align__(16) unsigned short P1[32 * 256];
  __shared__ float RSXP[8][32], RSHP[8][32];
  __shared__ float RSX[32], RSH[32];

  const int tid = threadIdx.x;
  const int a = blockIdx.x & 7;
  const int rowbase = (blockIdx.x >> 3) * 32;
  const int lane = tid & 63, w = tid >> 6;
  const int l16 = lane & 15, l4 = lane >> 4;
  const int n0 = w * 64;

  stage_split(P0, P1, inp, rowbase, a, tid);
  __syncthreads();
  {
    f32x4 XA[2][4];
#pragma unroll
    for (int mt = 0; mt < 2; ++mt)
#pragma unroll
      for (int nt = 0; nt < 4; ++nt) XA[mt][nt] = (f32x4){0.f, 0.f, 0.f, 0.f};
    mma64f(P0, ws + W1H_OFF + a * 65536, w * 4, lane, l16, l4, XA);
    mma64f(P1, ws + W1H_OFF + a * 65536, w * 4, lane, l16, l4, XA);
    mma64f(P0, ws + W1L_OFF + a * 65536, w * 4, lane, l16, l4, XA);
    __syncthreads();
#pragma unroll
    for (int nt = 0; nt < 4; ++nt) {
      int col = n0 + nt * 16 + l16;
      float bb = b1[a * 256 + col];
#pragma unroll
      for (int mt = 0; mt < 2; ++mt)
#pragma unroll
        for (int r = 0; r < 4; ++r) {
          float v = fmaxf(XA[mt][nt][r] + bb, 0.f);
          int row = mt * 16 + l4 * 4 + r;
          P0[((row << 8) + col) ^ ((row & 7) << 3)] = f2bf(v);
        }
    }
  }
  stage_single(P1, hin, rowbase, a, tid);
  __syncthreads();
  {
    int row = tid >> 3, qd = tid & 7;
    float sx = 0.f, sh = 0.f;
#pragma unroll
    for (int i = 0; i < 8; ++i) {
      int c = qd * 32 + i * 4;
      int idx = ((row << 8) + c) ^ ((row & 7) << 3);
      us4 vx = *(const us4*)(P0 + idx);
      us4 vh = *(const us4*)(P1 + idx);
      sx += bf2f(vx[0]) + bf2f(vx[1]) + bf2f(vx[2]) + bf2f(vx[3]);
      sh += bf2f(vh[0]) + bf2f(vh[1]) + bf2f(vh[2]) + bf2f(vh[3]);
    }
    RSXP[qd][row] = sx; RSHP[qd][row] = sh;
  }
  __syncthreads();
  if (tid < 32) {
    float sx = 0.f, sh = 0.f;
#pragma unroll
    for (int qd = 0; qd < 8; ++qd) { sx += RSXP[qd][tid]; sh += RSHP[qd][tid]; }
    RSX[tid] = sx; RSH[tid] = sh;
  }
  __syncthreads();

  const unsigned short* WihF = ws + WIH_OFF + a * 196608;
  const unsigned short* WhhF = ws + WHH_OFF + a * 196608;

  for (int nt = 0; nt < 4; ++nt) {
    const int col = n0 + nt * 16 + l16;
    const int cb = w * 4 + nt;               // gate-local col-block
    f32x4 R4[2], T4[2], G4[2];
#pragma unroll
    for (int mt = 0; mt < 2; ++mt) R4[mt] = (f32x4){0.f, 0.f, 0.f, 0.f};
    mma16f(P0, WihF, cb, lane, l16, l4, R4);
    mma16f(P1, WhhF, cb, lane, l16, l4, R4);
    {
      float bb = bih[a * 768 + col] + bhh[a * 768 + col];
#pragma unroll
      for (int mt = 0; mt < 2; ++mt)
#pragma unroll
        for (int r = 0; r < 4; ++r) {
          int row = mt * 16 + l4 * 4 + r;
          R4[mt][r] = sigm(R4[mt][r] + 0.5f * (RSX[row] + RSH[row]) + bb);
        }
    }
#pragma unroll
    for (int mt = 0; mt < 2; ++mt) T4[mt] = (f32x4){0.f, 0.f, 0.f, 0.f};
    mma16f(P1, WhhF, 32 + cb, lane, l16, l4, T4);
    {
      float bb = bhh[a * 768 + 512 + col];
#pragma unroll
      for (int mt = 0; mt < 2; ++mt)
#pragma unroll
        for (int r = 0; r < 4; ++r) {
          int row = mt * 16 + l4 * 4 + r;
          T4[mt][r] = R4[mt][r] * (T4[mt][r] + 0.5f * RSH[row] + bb);
        }
    }
#pragma unroll
    for (int mt = 0; mt < 2; ++mt) G4[mt] = (f32x4){0.f, 0.f, 0.f, 0.f};
    mma16f(P0, WihF, 32 + cb, lane, l16, l4, G4);
    {
      float bb = bih[a * 768 + 512 + col];
#pragma unroll
      for (int mt = 0; mt < 2; ++mt)
#pragma unroll
        for (int r = 0; r < 4; ++r) {
          int row = mt * 16 + l4 * 4 + r;
          T4[mt][r] = tanh_(G4[mt][r] + 0.5f * RSX[row] + bb + T4[mt][r]);
        }
    }
#pragma unroll
    for (int mt = 0; mt < 2; ++mt) G4[mt] = (f32x4){0.f, 0.f, 0.f, 0.f};
    mma16f(P0, WihF, 16 + cb, lane, l16, l4, G4);
    mma16f(P1, WhhF, 16 + cb, lane, l16, l4, G4);
    {
      float bb = bih[a * 768 + 256 + col] + bhh[a * 768 + 256 + col];
#pragma unroll
      for (int mt = 0; mt < 2; ++mt)
#pragma unroll
        for (int r = 0; r < 4; ++r) {
          int row = mt * 16 + l4 * 4 + r;
          float ig = sigm(G4[mt][r] + 0.5f * (RSX[row] + RSH[row]) + bb);
          float hv = bf2f(P1[((row << 8) + col) ^ ((row & 7) << 3)]);
          float ng = T4[mt][r];
          out[QSIZE + ((((rowbase + row) << 3) + a) << 8) + col]
              = ng + ig * (hv - ng);
        }
    }
  }
  __syncthreads();
  stage_single(P0, out + QSIZE, rowbase, a, tid);
  __syncthreads();
  if (w < 2) {
    f32x4 qa[2];
    qa[0] = (f32x4){0.f, 0.f, 0.f, 0.f};
    qa[1] = (f32x4){0.f, 0.f, 0.f, 0.f};
#pragma unroll
    for (int ks = 0; ks < 8; ++ks) {
      int row = w * 16 + l16;
      int idx = ((row << 8) + ks * 32 + 8 * l4) ^ ((row & 7) << 3);
      s8 af = *(const s8*)(P0 + idx);
#pragma unroll
      for (int nt = 0; nt < 2; ++nt) {
        s8 bw = *(const s8*)(ws + W2T_OFF + a * 8192 + nt * 4096 + ks * 512 + lane * 8);
        qa[nt] = __builtin_amdgcn_mfma_f32_16x16x32_bf16(af, bw, qa[nt], 0, 0, 0);
      }
    }
#pragma unroll
    for (int nt = 0; nt < 2; ++nt) {
      int col = nt * 16 + l16;
      if (col < 30) {
        float bb = b2[a * 30 + col];
#pragma unroll
        for (int r = 0; r < 4; ++r) {
          int row = w * 16 + l4 * 4 + r;
          out[(((rowbase + row) << 3) + a) * 30 + col] = fmaxf(qa[nt][r] + bb, 0.f);
        }
      }
    }
  }
}

extern "C" void kernel_launch(void* const* d_in, const int* in_sizes, int n_in,
                              void* d_out, int out_size, void* d_ws, size_t ws_size,
                              hipStream_t stream) {
  const float* inputs = (const float*)d_in[0];
  const float* hidden = (const float*)d_in[1];
  const float* fc1w   = (const float*)d_in[2];
  const float* fc1b   = (const float*)d_in[3];
  const float* rihw   = (const float*)d_in[4];
  const float* rihb   = (const float*)d_in[5];
  const float* rhhw   = (const float*)d_in[6];
  const float* rhhb   = (const float*)d_in[7];
  const float* fc2w   = (const float*)d_in[8];
  const float* fc2b   = (const float*)d_in[9];
  unsigned short* ws  = (unsigned short*)d_ws;
  float* out          = (float*)d_out;

  hipLaunchKernelGGL(prep_weights, dim3(3648), dim3(256), 0, stream,
                     fc1w, rihw, rhhw, fc2w, ws);

  if (ws_size >= WS_NEED_NEW) {
    hipLaunchKernelGGL(k1_fc1, dim3(1024), dim3(256), 0, stream,
                       inputs, hidden, fc1b, ws);
    hipLaunchKernelGGL(k2_fused, dim3(1024), dim3(512), 0, stream,
                       rihb, rhhb, fc2b, ws, out);
  } else {
    hipLaunchKernelGGL(fused_agent_rnn, dim3(1024), dim3(256), 0, stream,
                       inputs, hidden, fc1b, rihb, rhhb, fc2b, ws, out);
  }
}

// Round 15
// 88.024 us; speedup vs baseline: 1.5138x; 1.0809x over previous
//
#include <hip/hip_runtime.h>

// ---------------------------------------------------------------------------
// LatentMixtureAllRNNAgent: per-agent fc1 -> GRU cell -> fc2 on MI355X.
// Round 15: round-14 fused structure, registers squeezed to the 128-reg
// residency step. r14 lesson: 512-thr block at 132 regs -> 3 waves/SIMD ->
// quantizes to 1 block/CU (Occ 21%); the 16-VGPR hloc array was the excess.
// Fix: h stashed in the dead T accumulators (AGPRs) instead of hloc, and
// __launch_bounds__(512,4) pins the cap at 128. Target 64V+64A = 128 ->
// 4 waves/SIMD -> 2 blocks/CU (50% occ).
// Numerics identical to round 14 (absmax 1.0).
// ---------------------------------------------------------------------------

typedef __attribute__((ext_vector_type(4))) float f32x4;
typedef __attribute__((ext_vector_type(8))) short s8;     // 8 bf16 (4 VGPRs)
typedef __attribute__((ext_vector_type(4))) unsigned short us4;
typedef __attribute__((ext_vector_type(8))) unsigned short us8;

#define QSIZE   983040      /* 32768*30 */
#define W1H_OFF 0
#define W1L_OFF 524288
#define WIH_OFF 1048576
#define WHH_OFF 2621440
#define W2T_OFF 4194304
#define XB_OFF  4259840                 /* X fragments:   8a x 256rb x 4096 */
#define HB_OFF  12648448                /* h_in fragments: same */
#define RSX_U   21037056                /* f32 rowsum(x):   8a x 4096 rows  */
#define RSH_U   21102592                /* f32 rowsum(h_in): same           */
#define WS_NEED_NEW 42336256ull        /* bytes */

static __device__ __forceinline__ unsigned short f2bf(float f) {
  union { float f; unsigned u; } v; v.f = f;
  unsigned r = v.u + 0x7FFFu + ((v.u >> 16) & 1u);   // RNE
  return (unsigned short)(r >> 16);
}
static __device__ __forceinline__ float bf2f(unsigned short u) {
  union { unsigned u; float f; } v; v.u = ((unsigned)u) << 16;
  return v.f;
}
static __device__ __forceinline__ float sigm(float x) {
  return 1.0f / (1.0f + __expf(-x));
}
static __device__ __forceinline__ float tanh_(float x) {
  return 1.0f - 2.0f / (__expf(2.0f * x) + 1.0f);
}

// ---- prep: f32 [a][k][n] -> bf16 fragment layout [a][cb][ks][l4][l16][8] ---
__global__ void prep_weights(const float* __restrict__ fc1w,
                             const float* __restrict__ rihw,
                             const float* __restrict__ rhhw,
                             const float* __restrict__ fc2w,
                             unsigned short* __restrict__ ws) {
  int q = blockIdx.x * 256 + threadIdx.x;   // one us4 (4 k-values) per thread
  if (q < 131072) {                         // fc1: hi + lo, 8a x 16cb x 1024
    int a = q >> 14, rem = q & 16383;
    int cb = rem >> 10, s = rem & 1023;
    int ks = s >> 7, l4 = (s >> 5) & 3, l16 = (s >> 1) & 15, hf = s & 1;
    int n = cb * 16 + l16, k0 = ks * 32 + l4 * 8 + hf * 4;
    const float* sp = fc1w + a * 65536 + k0 * 256 + n;
    float v0 = sp[0], v1 = sp[256], v2 = sp[512], v3 = sp[768];
    us4 hi = { f2bf(v0), f2bf(v1), f2bf(v2), f2bf(v3) };
    us4 lo = { f2bf(v0 - bf2f(hi[0])), f2bf(v1 - bf2f(hi[1])),
               f2bf(v2 - bf2f(hi[2])), f2bf(v3 - bf2f(hi[3])) };
    int o = a * 65536 + cb * 4096 + ks * 512 + l4 * 128 + l16 * 8 + hf * 4;
    *(us4*)(ws + W1H_OFF + o) = hi;
    *(us4*)(ws + W1L_OFF + o) = lo;
  } else if (q < 524288) {                  // rnn_ih centered: 8a x 48cb
    int t = q - 131072;
    int a = t / 49152, rem = t % 49152;
    int cb = rem >> 10, s = rem & 1023;
    int ks = s >> 7, l4 = (s >> 5) & 3, l16 = (s >> 1) & 15, hf = s & 1;
    int n = cb * 16 + l16, k0 = ks * 32 + l4 * 8 + hf * 4;
    const float* sp = rihw + a * 196608 + k0 * 768 + n;
    us4 v = { f2bf(sp[0] - 0.5f), f2bf(sp[768] - 0.5f),
              f2bf(sp[1536] - 0.5f), f2bf(sp[2304] - 0.5f) };
    *(us4*)(ws + WIH_OFF + a * 196608 + cb * 4096 + ks * 512 + l4 * 128
            + l16 * 8 + hf * 4) = v;
  } else if (q < 917504) {                  // rnn_hh centered
    int t = q - 524288;
    int a = t / 49152, rem = t % 49152;
    int cb = rem >> 10, s = rem & 1023;
    int ks = s >> 7, l4 = (s >> 5) & 3, l16 = (s >> 1) & 15, hf = s & 1;
    int n = cb * 16 + l16, k0 = ks * 32 + l4 * 8 + hf * 4;
    const float* sp = rhhw + a * 196608 + k0 * 768 + n;
    us4 v = { f2bf(sp[0] - 0.5f), f2bf(sp[768] - 0.5f),
              f2bf(sp[1536] - 0.5f), f2bf(sp[2304] - 0.5f) };
    *(us4*)(ws + WHH_OFF + a * 196608 + cb * 4096 + ks * 512 + l4 * 128
            + l16 * 8 + hf * 4) = v;
  } else if (q < 933888) {                  // fc2: 8a x 2cb, pad n>=30 -> 0
    int t = q - 917504;
    int a = t >> 11, rem = t & 2047;
    int cb = rem >> 10, s = rem & 1023;
    int ks = s >> 7, l4 = (s >> 5) & 3, l16 = (s >> 1) & 15, hf = s & 1;
    int n = cb * 16 + l16, k0 = ks * 32 + l4 * 8 + hf * 4;
    us4 v = { 0, 0, 0, 0 };
    if (n < 30) {
      const float* sp = fc2w + a * 7680 + k0 * 30 + n;
      v = (us4){ f2bf(sp[0]), f2bf(sp[30]), f2bf(sp[60]), f2bf(sp[90]) };
    }
    *(us4*)(ws + W2T_OFF + a * 8192 + cb * 4096 + ks * 512 + l4 * 128
            + l16 * 8 + hf * 4) = v;
  }
}

// ------- stage 32x256 f32 tile -> split bf16 (hi p0, lo p1), 256 thr --------
static __device__ __forceinline__ void stage_split(unsigned short* p0,
                                                   unsigned short* p1,
                                                   const float* __restrict__ src,
                                                   int rowbase, int a, int tid) {
#pragma unroll
  for (int k = 0; k < 8; ++k) {
    int j = tid + k * 256;
    int r = j >> 6;
    int c4 = (j & 63) << 2;
    const float* p = src + ((((rowbase + r) << 3) + a) << 8) + c4;
    float4 v = *(const float4*)p;
    us4 hi = { f2bf(v.x), f2bf(v.y), f2bf(v.z), f2bf(v.w) };
    us4 lo = { f2bf(v.x - bf2f(hi[0])), f2bf(v.y - bf2f(hi[1])),
               f2bf(v.z - bf2f(hi[2])), f2bf(v.w - bf2f(hi[3])) };
    int idx = ((r << 8) + c4) ^ ((r & 7) << 3);   // XOR swizzle (16B blocks)
    *(us4*)(p0 + idx) = hi;
    *(us4*)(p1 + idx) = lo;
  }
}

// ------------- stage 32x256 f32 tile -> single bf16 plane, 256 thr ----------
static __device__ __forceinline__ void stage_single(unsigned short* p,
                                                    const float* __restrict__ src,
                                                    int rowbase, int a, int tid) {
#pragma unroll
  for (int k = 0; k < 8; ++k) {
    int j = tid + k * 256;
    int r = j >> 6;
    int c4 = (j & 63) << 2;
    const float* sp = src + ((((rowbase + r) << 3) + a) << 8) + c4;
    float4 v = *(const float4*)sp;
    us4 hi = { f2bf(v.x), f2bf(v.y), f2bf(v.z), f2bf(v.w) };
    int idx = ((r << 8) + c4) ^ ((r & 7) << 3);
    *(us4*)(p + idx) = hi;
  }
}

// ---- 32x64 GEMM over K=256, B from fragment layout (fallback only) ---------
static __device__ __forceinline__ void mma64f(const unsigned short* lds,
                                              const unsigned short* __restrict__ wf,
                                              int cb0, int lane, int l16, int l4,
                                              f32x4 (&acc)[2][4]) {
#pragma unroll
  for (int ks = 0; ks < 8; ++ks) {
    s8 af[2], bw[4];
#pragma unroll
    for (int mt = 0; mt < 2; ++mt) {
      int row = mt * 16 + l16;
      int idx = ((row << 8) + ks * 32 + 8 * l4) ^ ((row & 7) << 3);
      af[mt] = *(const s8*)(lds + idx);
    }
#pragma unroll
    for (int nt = 0; nt < 4; ++nt)
      bw[nt] = *(const s8*)(wf + (cb0 + nt) * 4096 + ks * 512 + lane * 8);
#pragma unroll
    for (int mt = 0; mt < 2; ++mt)
#pragma unroll
      for (int nt = 0; nt < 4; ++nt)
        acc[mt][nt] = __builtin_amdgcn_mfma_f32_16x16x32_bf16(
            af[mt], bw[nt], acc[mt][nt], 0, 0, 0);
  }
}

// ---- 32x16 GEMM over K=256, fragment B (fallback kernel) -------------------
static __device__ __forceinline__ void mma16f(const unsigned short* lds,
                                              const unsigned short* __restrict__ wf,
                                              int cb, int lane, int l16, int l4,
                                              f32x4 (&acc)[2]) {
#pragma unroll
  for (int ks = 0; ks < 8; ++ks) {
    s8 bw = *(const s8*)(wf + cb * 4096 + ks * 512 + lane * 8);
#pragma unroll
    for (int mt = 0; mt < 2; ++mt) {
      int row = mt * 16 + l16;
      int idx = ((row << 8) + ks * 32 + 8 * l4) ^ ((row & 7) << 3);
      s8 af = *(const s8*)(lds + idx);
      acc[mt] = __builtin_amdgcn_mfma_f32_16x16x32_bf16(af, bw, acc[mt], 0, 0, 0);
    }
  }
}

// ====== K1: fc1 (fused 3-pass) -> X fragments; h_in frags; rowsums ==========
__global__ __launch_bounds__(256, 2) void k1_fc1(
    const float* __restrict__ inp, const float* __restrict__ hin,
    const float* __restrict__ b1, unsigned short* __restrict__ ws) {
  __shared__ __align__(16) unsigned short P0[32 * 256];
  __shared__ __align__(16) unsigned short P1[32 * 256];
  __shared__ float RSXP[8][32], RSHP[8][32];
  const int tid = threadIdx.x;
  const int a = blockIdx.x & 7;
  const int rt = blockIdx.x >> 3;
  const int rowbase = rt * 32;
  const int lane = tid & 63, w = tid >> 6;
  const int l16 = lane & 15, l4 = lane >> 4;
  const int n0 = w * 64;

  stage_split(P0, P1, inp, rowbase, a, tid);
  __syncthreads();

  f32x4 XA[2][4];
#pragma unroll
  for (int mt = 0; mt < 2; ++mt)
#pragma unroll
    for (int nt = 0; nt < 4; ++nt) XA[mt][nt] = (f32x4){0.f, 0.f, 0.f, 0.f};

  {  // fused: per ks load W1H once (feeds P0 and P1 passes) + W1L
    const unsigned short* WH = ws + W1H_OFF + a * 65536 + (w * 4) * 4096 + lane * 8;
    const unsigned short* WL = ws + W1L_OFF + a * 65536 + (w * 4) * 4096 + lane * 8;
#pragma unroll 2
    for (int ks = 0; ks < 8; ++ks) {
      s8 af0[2], af1[2];
#pragma unroll
      for (int mt = 0; mt < 2; ++mt) {
        int row = mt * 16 + l16;
        int idx = ((row << 8) + ks * 32 + 8 * l4) ^ ((row & 7) << 3);
        af0[mt] = *(const s8*)(P0 + idx);
        af1[mt] = *(const s8*)(P1 + idx);
      }
      s8 bh[4], bl[4];
#pragma unroll
      for (int nt = 0; nt < 4; ++nt) {
        bh[nt] = *(const s8*)(WH + nt * 4096 + ks * 512);
        bl[nt] = *(const s8*)(WL + nt * 4096 + ks * 512);
      }
#pragma unroll
      for (int mt = 0; mt < 2; ++mt)
#pragma unroll
        for (int nt = 0; nt < 4; ++nt) {
          XA[mt][nt] = __builtin_amdgcn_mfma_f32_16x16x32_bf16(af0[mt], bh[nt], XA[mt][nt], 0, 0, 0);
          XA[mt][nt] = __builtin_amdgcn_mfma_f32_16x16x32_bf16(af1[mt], bh[nt], XA[mt][nt], 0, 0, 0);
          XA[mt][nt] = __builtin_amdgcn_mfma_f32_16x16x32_bf16(af0[mt], bl[nt], XA[mt][nt], 0, 0, 0);
        }
    }
  }
  __syncthreads();                           // all LDS reads done

  // write x bf16 -> P0 (swizzled); stage h_in bf16 -> P1 (swizzled)
#pragma unroll
  for (int nt = 0; nt < 4; ++nt) {
    int col = n0 + nt * 16 + l16;
    float bb = b1[a * 256 + col];
#pragma unroll
    for (int mt = 0; mt < 2; ++mt)
#pragma unroll
      for (int r = 0; r < 4; ++r) {
        float v = fmaxf(XA[mt][nt][r] + bb, 0.f);
        int row = mt * 16 + l4 * 4 + r;
        P0[((row << 8) + col) ^ ((row & 7) << 3)] = f2bf(v);
      }
  }
  stage_single(P1, hin, rowbase, a, tid);
  __syncthreads();

  // fragment-dump: P0 -> XF, P1 -> HF (contiguous us8 wave stores)
  const int rbg = (a << 8) + rt * 2;
#pragma unroll
  for (int i = 0; i < 4; ++i) {
    int c = tid + i * 256;                   // 0..1023 us8 chunks
    int rb = c >> 9, s = c & 511;            // s = ks*64 + l4*16 + l16
    int row = rb * 16 + (s & 15);
    int col = ((s >> 6) << 5) + (((s >> 4) & 3) << 3);
    int idx = ((row << 8) + col) ^ ((row & 7) << 3);
    *(us8*)(ws + XB_OFF + (rbg + rb) * 4096 + s * 8) = *(const us8*)(P0 + idx);
    *(us8*)(ws + HB_OFF + (rbg + rb) * 4096 + s * 8) = *(const us8*)(P1 + idx);
  }

  // exact f32 rowsums of the bf16 tiles -> ws (per-agent-row layout)
  {
    int row = tid >> 3, qd = tid & 7;
    float sx = 0.f, sh = 0.f;
#pragma unroll
    for (int i = 0; i < 8; ++i) {
      int c = qd * 32 + i * 4;
      int idx = ((row << 8) + c) ^ ((row & 7) << 3);
      us4 vx = *(const us4*)(P0 + idx);
      us4 vh = *(const us4*)(P1 + idx);
      sx += bf2f(vx[0]) + bf2f(vx[1]) + bf2f(vx[2]) + bf2f(vx[3]);
      sh += bf2f(vh[0]) + bf2f(vh[1]) + bf2f(vh[2]) + bf2f(vh[3]);
    }
    RSXP[qd][row] = sx; RSHP[qd][row] = sh;
  }
  __syncthreads();
  if (tid < 32) {
    float sx = 0.f, sh = 0.f;
#pragma unroll
    for (int qd = 0; qd < 8; ++qd) { sx += RSXP[qd][tid]; sh += RSHP[qd][tid]; }
    float* rsxg = (float*)(ws + RSX_U);
    float* rshg = (float*)(ws + RSH_U);
    rsxg[a * 4096 + rowbase + tid] = sx;
    rshg[a * 4096 + rowbase + tid] = sh;
  }
}

// ====== K2 fused: gates (8 waves = 8 col-slices) + fc2 tail, 128-reg fit ====
__global__ __launch_bounds__(512, 4) void k2_fused(
    const float* __restrict__ bih, const float* __restrict__ bhh,
    const float* __restrict__ b2, const unsigned short* __restrict__ ws,
    float* __restrict__ out) {
  __shared__ __align__(16) unsigned short AX[8192];   // X frags -> h bf16 (16KB)
  __shared__ __align__(16) unsigned short AH[8192];   // H frags (16KB)
  const int tid  = threadIdx.x;
  const int lane = tid & 63;
  const int w    = tid >> 6;                // 0..7 = col-slice
  const int a    = blockIdx.x & 7;          // agent == XCD
  const int rt   = blockIdx.x >> 3;         // 0..127
  const int rowbase = rt * 32;
  const int cs   = w;
  const int n0   = cs * 32;
  const int l16  = lane & 15, qr = lane >> 4;

  // stage A fragments once per block (all 8 waves share the same 32 rows)
  {
    const unsigned short* XFg = ws + XB_OFF + ((a << 8) + rt * 2) * 4096;
    const unsigned short* HFg = ws + HB_OFF + ((a << 8) + rt * 2) * 4096;
#pragma unroll
    for (int i = 0; i < 2; ++i) {
      int c = tid + i * 512;                // 0..1023 us8 chunks
      *(us8*)(AX + c * 8) = *(const us8*)(XFg + c * 8);
      *(us8*)(AH + c * 8) = *(const us8*)(HFg + c * 8);
    }
  }
  __syncthreads();

  const unsigned short* WihR = ws + WIH_OFF + a * 196608 + (cs * 2) * 4096 + lane * 8;
  const unsigned short* WhhR = ws + WHH_OFF + a * 196608 + (cs * 2) * 4096 + lane * 8;

  f32x4 R[2][2], I[2][2], T[2][2], G[2][2];
#pragma unroll
  for (int mt = 0; mt < 2; ++mt)
#pragma unroll
    for (int nt = 0; nt < 2; ++nt) {
      R[mt][nt] = (f32x4){0.f, 0.f, 0.f, 0.f};
      I[mt][nt] = (f32x4){0.f, 0.f, 0.f, 0.f};
      T[mt][nt] = (f32x4){0.f, 0.f, 0.f, 0.f};
      G[mt][nt] = (f32x4){0.f, 0.f, 0.f, 0.f};
    }

  // ---- single pass: 4 LDS A-reads + 12 global B-loads + 24 MFMA per ks ----
#pragma unroll 2
  for (int ks = 0; ks < 8; ++ks) {
    const int ko = ks * 512 + lane * 8;
    s8 ax[2], ah[2];
#pragma unroll
    for (int mt = 0; mt < 2; ++mt) {
      ax[mt] = *(const s8*)(AX + mt * 4096 + ko);
      ah[mt] = *(const s8*)(AH + mt * 4096 + ko);
    }
    const int kg = ks * 512;
    s8 bxr[2], bhr[2], bxi[2], bhi[2], bxn[2], bhn[2];
#pragma unroll
    for (int nt = 0; nt < 2; ++nt) {
      bxr[nt] = *(const s8*)(WihR + nt * 4096 + kg);
      bhr[nt] = *(const s8*)(WhhR + nt * 4096 + kg);
      bxi[nt] = *(const s8*)(WihR + (16 + nt) * 4096 + kg);
      bhi[nt] = *(const s8*)(WhhR + (16 + nt) * 4096 + kg);
      bxn[nt] = *(const s8*)(WihR + (32 + nt) * 4096 + kg);
      bhn[nt] = *(const s8*)(WhhR + (32 + nt) * 4096 + kg);
    }
#pragma unroll
    for (int mt = 0; mt < 2; ++mt)
#pragma unroll
      for (int nt = 0; nt < 2; ++nt) {
        R[mt][nt] = __builtin_amdgcn_mfma_f32_16x16x32_bf16(ax[mt], bxr[nt], R[mt][nt], 0, 0, 0);
        R[mt][nt] = __builtin_amdgcn_mfma_f32_16x16x32_bf16(ah[mt], bhr[nt], R[mt][nt], 0, 0, 0);
        I[mt][nt] = __builtin_amdgcn_mfma_f32_16x16x32_bf16(ax[mt], bxi[nt], I[mt][nt], 0, 0, 0);
        I[mt][nt] = __builtin_amdgcn_mfma_f32_16x16x32_bf16(ah[mt], bhi[nt], I[mt][nt], 0, 0, 0);
        G[mt][nt] = __builtin_amdgcn_mfma_f32_16x16x32_bf16(ax[mt], bxn[nt], G[mt][nt], 0, 0, 0);
        T[mt][nt] = __builtin_amdgcn_mfma_f32_16x16x32_bf16(ah[mt], bhn[nt], T[mt][nt], 0, 0, 0);
      }
  }

  // ---- epilogue: gates, combine (hv from AH bf16), store h; h kept in T ---
  const float* rsxg = (const float*)(ws + RSX_U) + a * 4096 + rowbase;
  const float* rshg = (const float*)(ws + RSH_U) + a * 4096 + rowbase;
#pragma unroll
  for (int mt = 0; mt < 2; ++mt) {
    float4 sx4 = *(const float4*)(rsxg + mt * 16 + qr * 4);
    float4 sh4 = *(const float4*)(rshg + mt * 16 + qr * 4);
    float rsx[4] = { sx4.x, sx4.y, sx4.z, sx4.w };
    float rsh[4] = { sh4.x, sh4.y, sh4.z, sh4.w };
#pragma unroll
    for (int nt = 0; nt < 2; ++nt) {
      int col = n0 + nt * 16 + l16;
      float br = bih[a * 768 + col] + bhh[a * 768 + col];
      float bi = bih[a * 768 + 256 + col] + bhh[a * 768 + 256 + col];
      float bnh = bhh[a * 768 + 512 + col];
      float bni = bih[a * 768 + 512 + col];
#pragma unroll
      for (int r = 0; r < 4; ++r) {
        float rg = sigm(R[mt][nt][r] + 0.5f * (rsx[r] + rsh[r]) + br);
        float t  = rg * (T[mt][nt][r] + 0.5f * rsh[r] + bnh);
        float ng = tanh_(G[mt][nt][r] + 0.5f * rsx[r] + bni + t);
        float ig = sigm(I[mt][nt][r] + 0.5f * (rsx[r] + rsh[r]) + bi);
        int row = mt * 16 + qr * 4 + r;
        int flat = ((rowbase + row) << 3) + a;
        int hidx = mt * 4096 + cs * 512 + (nt * 2 + (l16 >> 3)) * 128
                 + (qr * 4 + r) * 8 + (l16 & 7);
        float hv = bf2f(AH[hidx]);
        float h = ng + ig * (hv - ng);
        out[QSIZE + (flat << 8) + col] = h;
        T[mt][nt][r] = h;                   // stash in dead accumulator (AGPR)
      }
    }
  }
  __syncthreads();   // all gate-loop AX reads complete

  // write h bf16 -> AX (swizzled 32x256 row-major) for fc2
#pragma unroll
  for (int mt = 0; mt < 2; ++mt)
#pragma unroll
    for (int nt = 0; nt < 2; ++nt)
#pragma unroll
      for (int r = 0; r < 4; ++r) {
        int row = mt * 16 + qr * 4 + r;
        int col = n0 + nt * 16 + l16;
        AX[((row << 8) + col) ^ ((row & 7) << 3)] = f2bf(T[mt][nt][r]);
      }
  __syncthreads();

  // ---- fc2 tail: waves 0-1, 16 rows each (k3's proven body) ----
  if (w < 2) {
    f32x4 qa[2];
    qa[0] = (f32x4){0.f, 0.f, 0.f, 0.f};
    qa[1] = (f32x4){0.f, 0.f, 0.f, 0.f};
#pragma unroll
    for (int ks = 0; ks < 8; ++ks) {
      int row = w * 16 + l16;
      int idx = ((row << 8) + ks * 32 + 8 * qr) ^ ((row & 7) << 3);
      s8 af = *(const s8*)(AX + idx);
#pragma unroll
      for (int nt = 0; nt < 2; ++nt) {
        s8 bw = *(const s8*)(ws + W2T_OFF + a * 8192 + nt * 4096 + ks * 512 + lane * 8);
        qa[nt] = __builtin_amdgcn_mfma_f32_16x16x32_bf16(af, bw, qa[nt], 0, 0, 0);
      }
    }
#pragma unroll
    for (int nt = 0; nt < 2; ++nt) {
      int col = nt * 16 + l16;
      if (col < 30) {
        float bb = b2[a * 30 + col];
#pragma unroll
        for (int r = 0; r < 4; ++r) {
          int row = w * 16 + qr * 4 + r;
          out[(((rowbase + row) << 3) + a) * 30 + col] = fmaxf(qa[nt][r] + bb, 0.f);
        }
      }
    }
  }
}

// ======= fallback (ws too small for XF/HF): fused kernel, fragment W ========
__global__ __launch_bounds__(256, 2) void fused_agent_rnn(
    const float* __restrict__ inp,  const float* __restrict__ hin,
    const float* __restrict__ b1,   const float* __restrict__ bih,
    const float* __restrict__ bhh,  const float* __restrict__ b2,
    const unsigned short* __restrict__ ws, float* __restrict__ out) {
  __shared__ __align__(16) unsigned short P0[32 * 256];
  __shared__ __align__(16) unsigned short P1[32 * 256];
  __shared__ float RSXP[8][32], RSHP[8][32];
  __shared__ float RSX[32], RSH[32];

  const int tid = threadIdx.x;
  const int a = blockIdx.x & 7;
  const int rowbase = (blockIdx.x >> 3) * 32;
  const int lane = tid & 63, w = tid >> 6;
  const int l16 = lane & 15, l4 = lane >> 4;
  const int n0 = w * 64;

  stage_split(P0, P1, inp, rowbase, a, tid);
  __syncthreads();
  {
    f32x4 XA[2][4];
#pragma unroll
    for (int mt = 0; mt < 2; ++mt)
#pragma unroll
      for (int nt = 0; nt < 4; ++nt) XA[mt][nt] = (f32x4){0.f, 0.f, 0.f, 0.f};
    mma64f(P0, ws + W1H_OFF + a * 65536, w * 4, lane, l16, l4, XA);
    mma64f(P1, ws + W1H_OFF + a * 65536, w * 4, lane, l16, l4, XA);
    mma64f(P0, ws + W1L_OFF + a * 65536, w * 4, lane, l16, l4, XA);
    __syncthreads();
#pragma unroll
    for (int nt = 0; nt < 4; ++nt) {
      int col = n0 + nt * 16 + l16;
      float bb = b1[a * 256 + col];
#pragma unroll
      for (int mt = 0; mt < 2; ++mt)
#pragma unroll
        for (int r = 0; r < 4; ++r) {
          float v = fmaxf(XA[mt][nt][r] + bb, 0.f);
          int row = mt * 16 + l4 * 4 + r;
          P0[((row << 8) + col) ^ ((row & 7) << 3)] = f2bf(v);
        }
    }
  }
  stage_single(P1, hin, rowbase, a, tid);
  __syncthreads();
  {
    int row = tid >> 3, qd = tid & 7;
    float sx = 0.f, sh = 0.f;
#pragma unroll
    for (int i = 0; i < 8; ++i) {
      int c = qd * 32 + i * 4;
      int idx = ((row << 8) + c) ^ ((row & 7) << 3);
      us4 vx = *(const us4*)(P0 + idx);
      us4 vh = *(const us4*)(P1 + idx);
      sx += bf2f(vx[0]) + bf2f(vx[1]) + bf2f(vx[2]) + bf2f(vx[3]);
      sh += bf2f(vh[0]) + bf2f(vh[1]) + bf2f(vh[2]) + bf2f(vh[3]);
    }
    RSXP[qd][row] = sx; RSHP[qd][row] = sh;
  }
  __syncthreads();
  if (tid < 32) {
    float sx = 0.f, sh = 0.f;
#pragma unroll
    for (int qd = 0; qd < 8; ++qd) { sx += RSXP[qd][tid]; sh += RSHP[qd][tid]; }
    RSX[tid] = sx; RSH[tid] = sh;
  }
  __syncthreads();

  const unsigned short* WihF = ws + WIH_OFF + a * 196608;
  const unsigned short* WhhF = ws + WHH_OFF + a * 196608;

  for (int nt = 0; nt < 4; ++nt) {
    const int col = n0 + nt * 16 + l16;
    const int cb = w * 4 + nt;               // gate-local col-block
    f32x4 R4[2], T4[2], G4[2];
#pragma unroll
    for (int mt = 0; mt < 2; ++mt) R4[mt] = (f32x4){0.f, 0.f, 0.f, 0.f};
    mma16f(P0, WihF, cb, lane, l16, l4, R4);
    mma16f(P1, WhhF, cb, lane, l16, l4, R4);
    {
      float bb = bih[a * 768 + col] + bhh[a * 768 + col];
#pragma unroll
      for (int mt = 0; mt < 2; ++mt)
#pragma unroll
        for (int r = 0; r < 4; ++r) {
          int row = mt * 16 + l4 * 4 + r;
          R4[mt][r] = sigm(R4[mt][r] + 0.5f * (RSX[row] + RSH[row]) + bb);
        }
    }
#pragma unroll
    for (int mt = 0; mt < 2; ++mt) T4[mt] = (f32x4){0.f, 0.f, 0.f, 0.f};
    mma16f(P1, WhhF, 32 + cb, lane, l16, l4, T4);
    {
      float bb = bhh[a * 768 + 512 + col];
#pragma unroll
      for (int mt = 0; mt < 2; ++mt)
#pragma unroll
        for (int r = 0; r < 4; ++r) {
          int row = mt * 16 + l4 * 4 + r;
          T4[mt][r] = R4[mt][r] * (T4[mt][r] + 0.5f * RSH[row] + bb);
        }
    }
#pragma unroll
    for (int mt = 0; mt < 2; ++mt) G4[mt] = (f32x4){0.f, 0.f, 0.f, 0.f};
    mma16f(P0, WihF, 32 + cb, lane, l16, l4, G4);
    {
      float bb = bih[a * 768 + 512 + col];
#pragma unroll
      for (int mt = 0; mt < 2; ++mt)
#pragma unroll
        for (int r = 0; r < 4; ++r) {
          int row = mt * 16 + l4 * 4 + r;
          T4[mt][r] = tanh_(G4[mt][r] + 0.5f * RSX[row] + bb + T4[mt][r]);
        }
    }
#pragma unroll
    for (int mt = 0; mt < 2; ++mt) G4[mt] = (f32x4){0.f, 0.f, 0.f, 0.f};
    mma16f(P0, WihF, 16 + cb, lane, l16, l4, G4);
    mma16f(P1, WhhF, 16 + cb, lane, l16, l4, G4);
    {
      float bb = bih[a * 768 + 256 + col] + bhh[a * 768 + 256 + col];
#pragma unroll
      for (int mt = 0; mt < 2; ++mt)
#pragma unroll
        for (int r = 0; r < 4; ++r) {
          int row = mt * 16 + l4 * 4 + r;
          float ig = sigm(G4[mt][r] + 0.5f * (RSX[row] + RSH[row]) + bb);
          float hv = bf2f(P1[((row << 8) + col) ^ ((row & 7) << 3)]);
          float ng = T4[mt][r];
          out[QSIZE + ((((rowbase + row) << 3) + a) << 8) + col]
              = ng + ig * (hv - ng);
        }
    }
  }
  __syncthreads();
  stage_single(P0, out + QSIZE, rowbase, a, tid);
  __syncthreads();
  if (w < 2) {
    f32x4 qa[2];
    qa[0] = (f32x4){0.f, 0.f, 0.f, 0.f};
    qa[1] = (f32x4){0.f, 0.f, 0.f, 0.f};
#pragma unroll
    for (int ks = 0; ks < 8; ++ks) {
      int row = w * 16 + l16;
      int idx = ((row << 8) + ks * 32 + 8 * l4) ^ ((row & 7) << 3);
      s8 af = *(const s8*)(P0 + idx);
#pragma unroll
      for (int nt = 0; nt < 2; ++nt) {
        s8 bw = *(const s8*)(ws + W2T_OFF + a * 8192 + nt * 4096 + ks * 512 + lane * 8);
        qa[nt] = __builtin_amdgcn_mfma_f32_16x16x32_bf16(af, bw, qa[nt], 0, 0, 0);
      }
    }
#pragma unroll
    for (int nt = 0; nt < 2; ++nt) {
      int col = nt * 16 + l16;
      if (col < 30) {
        float bb = b2[a * 30 + col];
#pragma unroll
        for (int r = 0; r < 4; ++r) {
          int row = w * 16 + l4 * 4 + r;
          out[(((rowbase + row) << 3) + a) * 30 + col] = fmaxf(qa[nt][r] + bb, 0.f);
        }
      }
    }
  }
}

extern "C" void kernel_launch(void* const* d_in, const int* in_sizes, int n_in,
                              void* d_out, int out_size, void* d_ws, size_t ws_size,
                              hipStream_t stream) {
  const float* inputs = (const float*)d_in[0];
  const float* hidden = (const float*)d_in[1];
  const float* fc1w   = (const float*)d_in[2];
  const float* fc1b   = (const float*)d_in[3];
  const float* rihw   = (const float*)d_in[4];
  const float* rihb   = (const float*)d_in[5];
  const float* rhhw   = (const float*)d_in[6];
  const float* rhhb   = (const float*)d_in[7];
  const float* fc2w   = (const float*)d_in[8];
  const float* fc2b   = (const float*)d_in[9];
  unsigned short* ws  = (unsigned short*)d_ws;
  float* out          = (float*)d_out;

  hipLaunchKernelGGL(prep_weights, dim3(3648), dim3(256), 0, stream,
                     fc1w, rihw, rhhw, fc2w, ws);

  if (ws_size >= WS_NEED_NEW) {
    hipLaunchKernelGGL(k1_fc1, dim3(1024), dim3(256), 0, stream,
                       inputs, hidden, fc1b, ws);
    hipLaunchKernelGGL(k2_fused, dim3(1024), dim3(512), 0, stream,
                       rihb, rhhb, fc2b, ws, out);
  } else {
    hipLaunchKernelGGL(fused_agent_rnn, dim3(1024), dim3(256), 0, stream,
                       inputs, hidden, fc1b, rihb, rhhb, fc2b, ws, out);
  }
}